// Round 2
// baseline (627.813 us; speedup 1.0000x reference)
//
#include <hip/hip_runtime.h>

#define UNITS   114
#define SDIM    64
#define ACT     18
#define TSTEPS  64

// Globally-balanced bin-packed slots (placement identical to R4..R8):
//   rec:     E <= 704 edges, max in-degree <= 32. C=13/lane, <=2 posts/lane,
//            <=3 lanes/post. sensory: E == 512, max in-degree <= 20. C=9.
#define CR 13
#define CS 9
#define ER_CAP 704
#define MSTRIDE 24

#define LOG2E 1.4426950408889634f
#define EPS   1e-8f

typedef float v2f __attribute__((ext_vector_type(2)));
__device__ __forceinline__ v2f fma2(v2f a, v2f b, v2f c) {
  return __builtin_elementwise_fma(a, b, c);
}
__device__ __forceinline__ float bperm(int addr, float v) {
  return __int_as_float(__builtin_amdgcn_ds_bpermute(addr, __float_as_int(v)));
}
__device__ __forceinline__ float dperm(int addr, float v) {   // push: lane[addr>>2] <- v
  return __int_as_float(__builtin_amdgcn_ds_permute(addr, __float_as_int(v)));
}
// Wave-internal LDS phase separator (compiler fence + wave barrier, ~0 instr).
__device__ __forceinline__ void wsync() {
  __builtin_amdgcn_fence(__ATOMIC_ACQ_REL, "wavefront");
  __builtin_amdgcn_wave_barrier();
}
__device__ __forceinline__ int canonLane(int u) { return (u >= 64) ? (u - 64) : u; }

// k-th set bit of a 64-bit mask (k 0-based).
__device__ __forceinline__ int kthSetBit(unsigned long long m, int k) {
  int pos = 0;
#pragma unroll
  for (int ww = 32; ww >= 1; ww >>= 1) {
    const unsigned long long lowMask = ((1ull << ww) - 1ull);
    const int c = __popcll(m & lowMask);
    if (k >= c) { k -= c; m >>= ww; pos += ww; }
  }
  return pos;
}

// ---------------------------------------------------------------------------
// Build: R11 = R8 build + bank-aware per-lane slot permutation for the
// recurrent reads. Each lane's 13 slots are interchangeable (commutative
// accumulation; per-slot payload travels with the slot; merge logic is
// lane-level). Choose a per-lane bijection origSlot->newSlot so that each
// slot-instruction's 64 addresses have <=2 distinct per LDS bank (2-way is
// free on CDNA4; 3-4-way costs 1.3-1.6x). Pre-units 18..113 = exactly 3
// units/bank, so a greedy assignment gets nearly all instructions free.
// Greedy is wave-parallel: 13 candidate costs evaluated by 13 lanes,
// min-reduced by shfl; 64 lanes x 13 slots = 832 serial steps (~10 us once).
// ---------------------------------------------------------------------------
__global__ __launch_bounds__(64) void build_all(
    const float* __restrict__ w,  const float* __restrict__ mu,
    const float* __restrict__ sigma, const float* __restrict__ erev,
    const float* __restrict__ mask,
    const float* __restrict__ sw, const float* __restrict__ smu,
    const float* __restrict__ ssg, const float* __restrict__ serev,
    const float* __restrict__ smask,
    float4* __restrict__ recP4, float2* __restrict__ recP2, int* __restrict__ recAd,
    float4* __restrict__ senP4, float2* __restrict__ senP2, int* __restrict__ senAd,
    int* __restrict__ meta)
{
  const int l = threadIdx.x;
  __shared__ short ePre[ER_CAP], ePIdx[ER_CAP];
  __shared__ int deg[64], off[65];
  __shared__ int pLane[64], pF0[64], pRole[64];
  __shared__ int contIdx[64], contOwn[64], splitRole[64], split2[64], ownP[128];
  __shared__ int rcv[64];
  __shared__ short laneAddr[64*CR];          // pre unit per (lane, origSlot); 0 = dummy
  __shared__ signed char permS[64*CR];       // newSlot per (lane, origSlot)
  __shared__ unsigned char bmask[CR*32];     // residue bitmask per (newSlot, bank)

  contIdx[l] = 0; contOwn[l] = 0; splitRole[l] = -1; split2[l] = 0;
  ownP[2*l] = -1; ownP[2*l+1] = -1;
  pLane[l] = 0; pF0[l] = 0; pRole[l] = 0;

  if (blockIdx.x == 0) {
    int d = 0;
    if (l < 50) {
      for (int base = 18; base < 114; base += 16) {
        float mv[16];
#pragma unroll
        for (int q = 0; q < 16; ++q) mv[q] = mask[(base + q)*UNITS + l];
#pragma unroll
        for (int q = 0; q < 16; ++q) d += (mv[q] != 0.f) ? 1 : 0;
      }
    }
    deg[l] = (l < 50) ? d : 0;
    __syncthreads();
    if (l == 0) { int a = 0; for (int j = 0; j < 64; ++j) { off[j] = a; a += deg[j]; } off[64] = a; }
    __syncthreads();
    if (l < 50) {
      int o = off[l];
      for (int base = 18; base < 114; base += 16) {
        float mv[16];
#pragma unroll
        for (int q = 0; q < 16; ++q) mv[q] = mask[(base + q)*UNITS + l];
#pragma unroll
        for (int q = 0; q < 16; ++q)
          if (mv[q] != 0.f) { ePre[o] = (short)(base + q); ePIdx[o] = (short)l; ++o; }
      }
    }
    if (l == 0) {
      int lam = 0, f = 0, pc = 0;
      for (int p = 0; p < 50; ++p) {
        const int dd = deg[p];
        if (pc == 2 || f == CR || dd > 3*CR - f) { ++lam; f = 0; pc = 0; }
        if (lam > 63) lam = 63;
        pLane[p] = lam; pF0[p] = f; pRole[p] = pc;
        ownP[2*lam + pc] = p;
        const int owner = lam, role = pc; ++pc;
        const int take = dd < (CR - f) ? dd : (CR - f);
        f += take; int rem = dd - take;
        if (rem > 0) {
          splitRole[owner] = role; split2[owner] = (rem > CR) ? 1 : 0;
          ++lam; if (lam > 63) lam = 63; contIdx[lam] = 1; contOwn[lam] = owner; pc = 1;
          const int t2 = rem < CR ? rem : CR; f = t2; rem -= t2;
          if (rem > 0) { ++lam; if (lam > 63) lam = 63; contIdx[lam] = 2; contOwn[lam] = owner; pc = 1; f = rem; }
        }
      }
    }
    __syncthreads();
    int dA = (contIdx[l] == 1) ? contOwn[l] : -1;
    int dB = (contIdx[l] == 2) ? contOwn[l] : -1;
    rcv[l] = 0; __syncthreads();
    if (dA >= 0) rcv[dA] = 1;
    __syncthreads();
    { const unsigned long long rM = __ballot(rcv[l] != 0), dM = __ballot(dA < 0);
      if (dA < 0) dA = kthSetBit(~rM, __popcll(dM & ((1ull << l) - 1ull))); }
    __syncthreads();
    rcv[l] = 0; __syncthreads();
    if (dB >= 0) rcv[dB] = 1;
    __syncthreads();
    { const unsigned long long rM = __ballot(rcv[l] != 0), dM = __ballot(dB < 0);
      if (dB < 0) dB = kthSetBit(~rM, __popcll(dM & ((1ull << l) - 1ull))); }
    {
      int* M = meta + l * MSTRIDE;
      M[0] = dA * 4; M[1] = dB * 4;
      const float s1A = (splitRole[l] == 0) ? 1.f : 0.f, s1B = (splitRole[l] == 1) ? 1.f : 0.f;
      M[2] = __float_as_int(s1A); M[3] = __float_as_int(s1B);
      const float s2 = split2[l] ? 1.f : 0.f;
      M[4] = __float_as_int(s1A * s2); M[5] = __float_as_int(s1B * s2);
      const int uA = ownP[2*l], uB = ownP[2*l+1];
      M[6] = ((uA >= 0) ? uA : 128 + l) * 4;
      M[7] = ((uB >= 0) ? uB : 192 + l) * 4;
      M[8] = (uA >= 0) ? uA : 0;
      M[9] = (uB >= 0) ? uB : 0;
    }
    // ---- bank-aware slot permutation (R11) ----
    for (int i = l; i < 64*CR; i += 64) laneAddr[i] = 0;
    for (int i = l; i < CR*32; i += 64) bmask[i] = 0;
    __syncthreads();
    {
      const int E = off[64];
      for (int e = l; e < E; e += 64) {
        const int pj = ePIdx[e];
        const int r  = e - off[pj];
        const int dd = deg[pj], f0 = pF0[pj];
        const int take = dd < (CR - f0) ? dd : (CR - f0);
        int lane = pLane[pj], slot;
        if (r < take)            { slot = f0 + r; }
        else if (r < take + CR)  { lane += 1; slot = r - take; }
        else                     { lane += 2; slot = r - take - CR; }
        if (lane > 63) lane = 63;
        laneAddr[lane*CR + slot] = ePre[e];
      }
    }
    __syncthreads();
    for (int j = 0; j < 64; ++j) {
      int used = 0;
      for (int os = 0; os < CR; ++os) {
        const int u  = laneAddr[j*CR + os];
        const int bk = u & 31, res = u >> 5;
        int cost = 1 << 20;
        if (l < CR && !(used & (1 << l))) {
          const int m  = bmask[l*32 + bk];
          const int np = __popc(m | (1 << res));
          const int c0 = ((m >> res) & 1) ? 0 : (np <= 2 ? np : 100*np);
          cost = c0*16 + l;                  // tie-break: lowest slot
        }
        int mn = cost;
#pragma unroll
        for (int dlt = 1; dlt < 64; dlt <<= 1) {
          const int o = __shfl_xor(mn, dlt);
          mn = (o < mn) ? o : mn;
        }
        const int ns = mn & 15;
        used |= 1 << ns;
        if (l == 0) { bmask[ns*32 + bk] |= (unsigned char)(1 << res); permS[j*CR + os] = (signed char)ns; }
        wsync();
      }
    }
    __syncthreads();
    for (int t = l; t < CR*64; t += 64) {
      recP4[t] = make_float4(0.f,0.f,0.f,0.f); recP2[t] = make_float2(0.f,0.f); recAd[t] = 0;
    }
    __syncthreads();
    {
      const int E = off[64];
      for (int e = l; e < E; e += 64) {
        const int pre = ePre[e], pj = ePIdx[e];
        const int r  = e - off[pj];
        const int dd = deg[pj], f0 = pF0[pj], role0 = pRole[pj];
        const int take = dd < (CR - f0) ? dd : (CR - f0);
        int lane = pLane[pj], slot, role;
        if (r < take)            { slot = f0 + r;        role = role0; }
        else if (r < take + CR)  { lane += 1; slot = r - take;      role = 0; }
        else                     { lane += 2; slot = r - take - CR; role = 0; }
        if (lane > 63) lane = 63;
        const int idx = pre * UNITS + pj;
        const float sg = sigma[idx];
        const float nsgl = -sg * LOG2E, msl = mu[idx] * sg * LOG2E;
        const float wd = w[idx], wn = wd * erev[idx];
        const int tt = (int)permS[lane*CR + slot] * 64 + lane;   // permuted slot
        recP4[tt] = make_float4(nsgl, msl, role ? 0.f : wn, role ? 0.f : wd);
        recP2[tt] = role ? make_float2(wn, wd) : make_float2(0.f, 0.f);
        recAd[tt] = pre * 4;
      }
    }
  } else {
    int d = 0;
    {
      const int col = 50 + l;
      for (int base = 0; base < 64; base += 16) {
        float mv[16];
#pragma unroll
        for (int q = 0; q < 16; ++q) mv[q] = smask[(base + q)*UNITS + col];
#pragma unroll
        for (int q = 0; q < 16; ++q) d += (mv[q] != 0.f) ? 1 : 0;
      }
    }
    deg[l] = d;
    __syncthreads();
    if (l == 0) { int a = 0; for (int j = 0; j < 64; ++j) { off[j] = a; a += deg[j]; } off[64] = a; }
    __syncthreads();
    {
      int o = off[l]; const int col = 50 + l;
      for (int base = 0; base < 64; base += 16) {
        float mv[16];
#pragma unroll
        for (int q = 0; q < 16; ++q) mv[q] = smask[(base + q)*UNITS + col];
#pragma unroll
        for (int q = 0; q < 16; ++q)
          if (mv[q] != 0.f) { ePre[o] = (short)(base + q); ePIdx[o] = (short)l; ++o; }
      }
    }
    if (l == 0) {
      int lam = 0, f = 0, pc = 0;
      for (int p = 0; p < 64; ++p) {
        const int dd = deg[p];
        if (pc == 2 || f == CS || dd > 3*CS - f) { ++lam; f = 0; pc = 0; }
        if (lam > 63) lam = 63;
        pLane[p] = lam; pF0[p] = f; pRole[p] = pc;
        ownP[2*lam + pc] = p;
        const int owner = lam, role = pc; ++pc;
        const int take = dd < (CS - f) ? dd : (CS - f);
        f += take; int rem = dd - take;
        if (rem > 0) {
          splitRole[owner] = role; split2[owner] = (rem > CS) ? 1 : 0;
          ++lam; if (lam > 63) lam = 63; contIdx[lam] = 1; contOwn[lam] = owner; pc = 1;
          const int t2 = rem < CS ? rem : CS; f = t2; rem -= t2;
          if (rem > 0) { ++lam; if (lam > 63) lam = 63; contIdx[lam] = 2; contOwn[lam] = owner; pc = 1; f = rem; }
        }
      }
    }
    __syncthreads();
    int dA = (contIdx[l] == 1) ? contOwn[l] : -1;
    int dB = (contIdx[l] == 2) ? contOwn[l] : -1;
    rcv[l] = 0; __syncthreads();
    if (dA >= 0) rcv[dA] = 1;
    __syncthreads();
    { const unsigned long long rM = __ballot(rcv[l] != 0), dM = __ballot(dA < 0);
      if (dA < 0) dA = kthSetBit(~rM, __popcll(dM & ((1ull << l) - 1ull))); }
    __syncthreads();
    rcv[l] = 0; __syncthreads();
    if (dB >= 0) rcv[dB] = 1;
    __syncthreads();
    { const unsigned long long rM = __ballot(rcv[l] != 0), dM = __ballot(dB < 0);
      if (dB < 0) dB = kthSetBit(~rM, __popcll(dM & ((1ull << l) - 1ull))); }
    __syncthreads();
    int rA = (ownP[2*l]   >= 0) ? canonLane(50 + ownP[2*l])   : -1;
    int rB = (ownP[2*l+1] >= 0) ? canonLane(50 + ownP[2*l+1]) : -1;
    rcv[l] = 0; __syncthreads();
    if (rA >= 0) rcv[rA] = 1;
    __syncthreads();
    const int isRcvA = rcv[l];
    { const unsigned long long rM = __ballot(isRcvA != 0), dM = __ballot(rA < 0);
      if (rA < 0) rA = kthSetBit(~rM, __popcll(dM & ((1ull << l) - 1ull))); }
    __syncthreads();
    rcv[l] = 0; __syncthreads();
    if (rB >= 0) rcv[rB] = 1;
    __syncthreads();
    { const unsigned long long rM = __ballot(rcv[l] != 0), dM = __ballot(rB < 0);
      if (rB < 0) rB = kthSetBit(~rM, __popcll(dM & ((1ull << l) - 1ull))); }
    {
      int* M = meta + l * MSTRIDE;
      M[10] = dA * 4; M[11] = dB * 4;
      const float s1A = (splitRole[l] == 0) ? 1.f : 0.f, s1B = (splitRole[l] == 1) ? 1.f : 0.f;
      M[12] = __float_as_int(s1A); M[13] = __float_as_int(s1B);
      const float s2 = split2[l] ? 1.f : 0.f;
      M[14] = __float_as_int(s1A * s2); M[15] = __float_as_int(s1B * s2);
      M[16] = rA * 4; M[17] = rB * 4;
      M[18] = __float_as_int(isRcvA ? 1.f : 0.f);
      M[19] = __float_as_int(isRcvA ? 0.f : 1.f);
      const int pA = ownP[2*l], pB = ownP[2*l+1];
      M[20] = (pA >= 0) ? 50 + pA : 0;
      M[21] = (pB >= 0) ? 50 + pB : 0;
    }
    for (int t = l; t < CS*64; t += 64) {
      senP4[t] = make_float4(0.f,0.f,0.f,0.f); senP2[t] = make_float2(0.f,0.f); senAd[t] = 0;
    }
    __syncthreads();
    {
      const int E = off[64];
      for (int e = l; e < E; e += 64) {
        const int pre = ePre[e], pj = ePIdx[e];
        const int r  = e - off[pj];
        const int dd = deg[pj], f0 = pF0[pj], role0 = pRole[pj];
        const int take = dd < (CS - f0) ? dd : (CS - f0);
        int lane = pLane[pj], slot, role;
        if (r < take)            { slot = f0 + r;        role = role0; }
        else if (r < take + CS)  { lane += 1; slot = r - take;      role = 0; }
        else                     { lane += 2; slot = r - take - CS; role = 0; }
        if (lane > 63) lane = 63;
        const int col = 50 + pj;
        const int idx = pre * UNITS + col;
        const float sg = ssg[idx];
        const float nsgl = -sg * LOG2E, msl = smu[idx] * sg * LOG2E;
        const float wd = sw[idx], wn = wd * serev[idx];
        const int tt = slot * 64 + lane;
        senP4[tt] = make_float4(nsgl, msl, role ? 0.f : wn, role ? 0.f : wd);
        senP2[tt] = role ? make_float2(wn, wd) : make_float2(0.f, 0.f);
        senAd[tt] = pre * 4;
      }
    }
  }
}

// ---------------------------------------------------------------------------
// Run kernel: byte-identical to R10 (no run-time cost for the bank fix;
// only the prebuilt slot layout changed).
// ---------------------------------------------------------------------------
__global__ __launch_bounds__(64, 2) void ltc_run(
    const float* __restrict__ obs,     const float* __restrict__ hidden,
    const float* __restrict__ input_w, const float* __restrict__ input_b,
    const float* __restrict__ gleak,   const float* __restrict__ vleak,
    const float* __restrict__ cm,
    const float* __restrict__ q_w1, const float* __restrict__ q_b1,
    const float* __restrict__ q_w2, const float* __restrict__ q_b2,
    const float4* __restrict__ recP4, const float2* __restrict__ recP2,
    const int* __restrict__ recAd,
    const float4* __restrict__ senP4, const float2* __restrict__ senP2,
    const int* __restrict__ senAd,
    const int* __restrict__ meta, float* __restrict__ out, int B)
{
  const int l = threadIdx.x, b = blockIdx.x;
  __shared__ float mirror[256];   // [0..113] units, [128..255] scratch sinks
  char* mbase = (char*)mirror;

  float rNS[CR], rMS[CR]; v2f rWA[CR], rWB[CR]; int rad[CR];
#pragma unroll
  for (int s = 0; s < CR; ++s) {
    const float4 p4 = recP4[s*64 + l]; const float2 p2 = recP2[s*64 + l];
    rNS[s] = p4.x; rMS[s] = p4.y; rWA[s] = (v2f){p4.z, p4.w};
    rWB[s] = (v2f){p2.x, p2.y}; rad[s] = recAd[s*64 + l];
  }
  float sNS[CS], sMS[CS]; v2f sWA[CS], sWB[CS]; int sad[CS];
#pragma unroll
  for (int s = 0; s < CS; ++s) {
    const float4 p4 = senP4[s*64 + l]; const float2 p2 = senP2[s*64 + l];
    sNS[s] = p4.x; sMS[s] = p4.y; sWA[s] = (v2f){p4.z, p4.w};
    sWB[s] = (v2f){p2.x, p2.y}; sad[s] = senAd[s*64 + l];
  }

  const int* M = meta + l * MSTRIDE;
  const int   rPush1 = M[0], rPush2 = M[1];
  const v2f gR1A = {__int_as_float(M[2]), __int_as_float(M[2])};
  const v2f gR1B = {__int_as_float(M[3]), __int_as_float(M[3])};
  const v2f gR2A = {__int_as_float(M[4]), __int_as_float(M[4])};
  const v2f gR2B = {__int_as_float(M[5]), __int_as_float(M[5])};
  const int   rWrA = M[6], rWrB = M[7], rUA = M[8], rUB = M[9];
  const int   sPush1 = M[10], sPush2 = M[11];
  const v2f gS1A = {__int_as_float(M[12]), __int_as_float(M[12])};
  const v2f gS1B = {__int_as_float(M[13]), __int_as_float(M[13])};
  const v2f gS2A = {__int_as_float(M[14]), __int_as_float(M[14])};
  const v2f gS2B = {__int_as_float(M[15]), __int_as_float(M[15])};
  const int   sRtA = M[16], sRtB = M[17];
  const float sRndA = __int_as_float(M[18]), sRndB = __int_as_float(M[19]);
  const int   sUA = M[20], sUB = M[21];

  const float cmA  = cm[rUA]*6.f, glvA  = gleak[rUA]*vleak[rUA], cgA  = cm[rUA]*6.f + gleak[rUA] + EPS;
  const float cmB  = cm[rUB]*6.f, glvB  = gleak[rUB]*vleak[rUB], cgB  = cm[rUB]*6.f + gleak[rUB] + EPS;
  const float cmSA = cm[sUA]*6.f, glvSA = gleak[sUA]*vleak[sUA], cgSA = cm[sUA]*6.f + gleak[sUA] + EPS;
  const float cmSB = cm[sUB]*6.f, glvSB = gleak[sUB]*vleak[sUB], cgSB = cm[sUB]*6.f + gleak[sUB] + EPS;

  // Ownership flags + folded accumulator inits (R10b).
  const bool ownA  = (rWrA < 512), ownB  = (rWrB < 512);
  const bool ownSA = (sUA != 0),   ownSB = (sUB != 0);
  const v2f initRA = ownA  ? (v2f){glvA,  cgA}  : (v2f){0.f, EPS};
  const v2f initRB = ownB  ? (v2f){glvB,  cgB}  : (v2f){0.f, EPS};
  const v2f initSA = ownSA ? (v2f){glvSA, cgSA} : (v2f){0.f, EPS};
  const v2f initSB = ownSB ? (v2f){glvSB, cgSB} : (v2f){0.f, EPS};

  const int  iUnit = (l < 50) ? 64 + l : l;
  const int  iWr   = iUnit * 4;
  float vIn = hidden[(size_t)b*UNITS + iUnit];
  float vPA = hidden[(size_t)b*UNITS + rUA];
  float vPB = hidden[(size_t)b*UNITS + rUB];

  mirror[l] = hidden[(size_t)b*UNITS + l];
  if (l < 50) mirror[64 + l] = hidden[(size_t)b*UNITS + 64 + l];

  const float iw = input_w[l], ibv = input_b[l];
  const float* ob = obs + (size_t)b*(TSTEPS*SDIM) + l;

  // ---- prologue: full sensory eval for t=0 ----
  float aI, bI;
  {
    const float xi = fmaf(ob[0], iw, ibv);
    float uu[CS];
#pragma unroll
    for (int s = 0; s < CS; ++s) {
      float z = fmaf(bperm(sad[s], xi), sNS[s], sMS[s]);
      z = fminf(z, 30.f);
      uu[s] = 1.f + __builtin_amdgcn_exp2f(z);
    }
    float sg[CS];
#pragma unroll
    for (int q = 0; q < 4; ++q) {
      const float p = uu[2*q] * uu[2*q+1];
      const float r = __builtin_amdgcn_rcpf(p);
      sg[2*q]   = uu[2*q+1] * r;
      sg[2*q+1] = uu[2*q]   * r;
    }
    sg[8] = __builtin_amdgcn_rcpf(uu[8]);
    v2f cA = {0.f,0.f}, cB = {0.f,0.f};
#pragma unroll
    for (int s = 0; s < CS; ++s) {
      const v2f s2 = {sg[s], sg[s]};
      cA = fma2(sWA[s], s2, cA);
      cB = fma2(sWB[s], s2, cB);
    }
    const v2f m1 = {dperm(sPush1, cA.x), dperm(sPush1, cA.y)};
    const v2f m2 = {dperm(sPush2, cA.x), dperm(sPush2, cA.y)};
    v2f tA = fma2(gS1A, m1, cA); tA = fma2(gS2A, m2, tA);
    v2f tB = fma2(gS1B, m1, cB); tB = fma2(gS2B, m2, tB);
    const float rdA = __builtin_amdgcn_rcpf(cgSA + tA.y);
    const float aA = cmSA * rdA, bA = (glvSA + tA.x) * rdA;
    const float rdB = __builtin_amdgcn_rcpf(cgSB + tB.y);
    const float aB = cmSB * rdB, bB = (glvSB + tB.x) * rdB;
    const float ra1 = dperm(sRtA, aA), rb1 = dperm(sRtA, bA);
    const float ra2 = dperm(sRtB, aB), rb2 = dperm(sRtB, bB);
    aI = sRndA*ra1 + sRndB*ra2;
    bI = sRndA*rb1 + sRndB*rb2;
  }

  // pipeline state for next-step sensory (accumulators carry folded consts)
  float xiN = fmaf(ob[SDIM], iw, ibv);   // xi(1)
  float xrC = ob[2*SDIM];                // obs(2)
  float su[CS];
  v2f acA = initSA, acB = initSB;
  v2f tSA = {0.f,0.f}, tSB = {0.f,0.f};
  float aIn = 0.f, bIn = 0.f;

  // one rec unfold with an embedded chunk of next-step sensory work
  auto unfold = [&](auto chunk) {
    wsync();
    float uu[CR];
#pragma unroll
    for (int s = 0; s < CR; ++s) {
      const float pv = *(const float*)(mbase + rad[s]);
      const float z = fmaf(pv, rNS[s], rMS[s]);   // z <= 20.8 always: no clamp
      uu[s] = 1.f + __builtin_amdgcn_exp2f(z);
    }
    chunk();                    // independent sensory work fills stalls here
    float sg[CR];
#pragma unroll
    for (int q = 0; q < 5; ++q) {
      const float p = uu[2*q] * uu[2*q+1];
      const float r = __builtin_amdgcn_rcpf(p);
      sg[2*q]   = uu[2*q+1] * r;
      sg[2*q+1] = uu[2*q]   * r;
    }
    {   // triple-shared rcp for slots 10,11,12
      const float p01 = uu[10]*uu[11];
      const float r = __builtin_amdgcn_rcpf(p01*uu[12]);
      const float t12 = uu[12]*r;
      sg[10] = uu[11]*t12; sg[11] = uu[10]*t12; sg[12] = p01*r;
    }
    v2f a0 = initRA, a1 = {0.f,0.f}, b0 = initRB, b1 = {0.f,0.f};
#pragma unroll
    for (int s = 0; s < CR; ++s) {
      const v2f s2 = {sg[s], sg[s]};
      if (s & 1) { a1 = fma2(rWA[s], s2, a1); b1 = fma2(rWB[s], s2, b1); }
      else       { a0 = fma2(rWA[s], s2, a0); b0 = fma2(rWB[s], s2, b0); }
    }
    v2f aA = a0 + a1, aB = b0 + b1;
    const v2f m1 = {dperm(rPush1, aA.x), dperm(rPush1, aA.y)};
    const v2f m2 = {dperm(rPush2, aA.x), dperm(rPush2, aA.y)};
    v2f tA = fma2(gR1A, m1, aA); tA = fma2(gR2A, m2, tA);
    v2f tB = fma2(gR1B, m1, aB); tB = fma2(gR2B, m2, tB);
    const float dAq = tA.y, dBq = tB.y;                   // consts pre-folded
    const float rr = __builtin_amdgcn_rcpf(dAq * dBq);    // paired rcp
    vPA = fmaf(cmA, vPA, tA.x) * (dBq * rr);
    vPB = fmaf(cmB, vPB, tB.x) * (dAq * rr);
    vIn = fmaf(aI, vIn, bI);
    wsync();
    *(float*)(mbase + rWrA) = vPA;
    *(float*)(mbase + rWrB) = vPB;
    *(float*)(mbase + iWr)  = vIn;
  };

  auto sExp = [&](int s) {
    float z = fmaf(bperm(sad[s], xiN), sNS[s], sMS[s]);
    z = fminf(z, 30.f);         // KEEP: sensory z can reach ~75 unclamped
    su[s] = 1.f + __builtin_amdgcn_exp2f(z);
  };
  auto sPair = [&](int s0) {
    const float p = su[s0] * su[s0+1];
    const float r = __builtin_amdgcn_rcpf(p);
    const float g0 = su[s0+1] * r, g1 = su[s0] * r;
    acA = fma2(sWA[s0],   (v2f){g0,g0}, acA);
    acA = fma2(sWA[s0+1], (v2f){g1,g1}, acA);
    acB = fma2(sWB[s0],   (v2f){g0,g0}, acB);
    acB = fma2(sWB[s0+1], (v2f){g1,g1}, acB);
  };

#pragma unroll 1
  for (int t = 0; t < TSTEPS; ++t) {
    unfold([&]{ sExp(0); sExp(1); });
    unfold([&]{ sExp(2); sExp(3); sPair(0); });
    unfold([&]{ sExp(4); sExp(5); sPair(2); });
    unfold([&]{ sExp(6); sExp(7); sExp(8); sPair(4); });
    unfold([&]{
      // triple-shared rcp for sensory slots 6,7,8 + accumulate + merge
      const float p67 = su[6] * su[7];
      const float r = __builtin_amdgcn_rcpf(p67 * su[8]);
      const float t67 = su[8] * r;
      const float g6 = su[7]*t67, g7 = su[6]*t67, g8 = p67*r;
      acA = fma2(sWA[6], (v2f){g6,g6}, acA); acB = fma2(sWB[6], (v2f){g6,g6}, acB);
      acA = fma2(sWA[7], (v2f){g7,g7}, acA); acB = fma2(sWB[7], (v2f){g7,g7}, acB);
      acA = fma2(sWA[8], (v2f){g8,g8}, acA); acB = fma2(sWB[8], (v2f){g8,g8}, acB);
      const v2f m1 = {dperm(sPush1, acA.x), dperm(sPush1, acA.y)};
      const v2f m2 = {dperm(sPush2, acA.x), dperm(sPush2, acA.y)};
      tSA = fma2(gS1A, m1, acA); tSA = fma2(gS2A, m2, tSA);
      tSB = fma2(gS1B, m1, acB); tSB = fma2(gS2B, m2, tSB);
    });
    unfold([&]{
      // route (aI,bI) for next step to canonical lanes (consts pre-folded)
      const float dA_ = tSA.y, dB_ = tSB.y;
      const float rr = __builtin_amdgcn_rcpf(dA_ * dB_);   // paired rcp
      const float rdA = dB_ * rr, rdB = dA_ * rr;
      const float aA = cmSA * rdA, bA = tSA.x * rdA;
      const float aB = cmSB * rdB, bB = tSB.x * rdB;
      const float ra1 = dperm(sRtA, aA), rb1 = dperm(sRtA, bA);
      const float ra2 = dperm(sRtB, aB), rb2 = dperm(sRtB, bB);
      aIn = sRndA*ra1 + sRndB*ra2;
      bIn = sRndA*rb1 + sRndB*rb2;
    });
    // step boundary: rotate pipeline state
    aI = aIn; bI = bIn;
    xiN = fmaf(xrC, iw, ibv);                      // xi(t+2)
    const int tn = (t + 3 < TSTEPS) ? (t + 3) : (TSTEPS - 1);
    xrC = ob[tn * SDIM];                           // obs(t+3), clamped
    acA = initSA; acB = initSB;
  }
  wsync();

  // ---- outputs: h then Q head ----
  float* __restrict__ outH = out + (size_t)B * ACT;
  outH[(size_t)b*UNITS + l] = mirror[l];
  if (l < 50) outH[(size_t)b*UNITS + 64 + l] = mirror[64 + l];

  const int j2 = (l < 50) ? 64 + l : l;
  float h1 = q_b1[l], h2 = q_b1[j2];
  for (int i = 0; i < UNITS; ++i) {
    const float hv = mirror[i];
    h1 = fmaf(hv, q_w1[i*UNITS + l],  h1);
    h2 = fmaf(hv, q_w1[i*UNITS + j2], h2);
  }
  h1 = fmaxf(h1, 0.f); h2 = fmaxf(h2, 0.f);
  wsync();
  mirror[l] = h1;
  if (l < 50) mirror[64 + l] = h2;
  wsync();
  if (l < ACT) {
    float q = q_b2[l];
    for (int i = 0; i < UNITS; ++i) q = fmaf(mirror[i], q_w2[i*ACT + l], q);
    out[(size_t)b*ACT + l] = q;
  }
}

extern "C" void kernel_launch(void* const* d_in, const int* in_sizes, int n_in,
                              void* d_out, int out_size, void* d_ws, size_t ws_size,
                              hipStream_t stream)
{
  const float* obs           = (const float*)d_in[0];
  const float* hidden        = (const float*)d_in[1];
  const float* input_w       = (const float*)d_in[2];
  const float* input_b       = (const float*)d_in[3];
  const float* sensory_w     = (const float*)d_in[4];
  const float* sensory_mu    = (const float*)d_in[5];
  const float* sensory_sigma = (const float*)d_in[6];
  const float* sensory_erev  = (const float*)d_in[7];
  const float* sensory_mask  = (const float*)d_in[8];
  const float* w             = (const float*)d_in[9];
  const float* mu            = (const float*)d_in[10];
  const float* sigma         = (const float*)d_in[11];
  const float* erev          = (const float*)d_in[12];
  const float* mask          = (const float*)d_in[13];
  const float* gleak         = (const float*)d_in[14];
  const float* vleak         = (const float*)d_in[15];
  const float* cm            = (const float*)d_in[16];
  const float* q_w1          = (const float*)d_in[17];
  const float* q_b1          = (const float*)d_in[18];
  const float* q_w2          = (const float*)d_in[19];
  const float* q_b2          = (const float*)d_in[20];

  char* ws = (char*)d_ws;
  float4* recP4 = (float4*)(ws);            // 13*64*16 = 13312
  float2* recP2 = (float2*)(ws + 13312);    // 13*64*8  = 6656  -> 19968
  int*    recAd = (int*)   (ws + 19968);    // 13*64*4  = 3328  -> 23296
  float4* senP4 = (float4*)(ws + 23296);    // 9*64*16  = 9216  -> 32512
  float2* senP2 = (float2*)(ws + 32512);    // 9*64*8   = 4608  -> 37120
  int*    senAd = (int*)   (ws + 37120);    // 9*64*4   = 2304  -> 39424
  int*    meta  = (int*)   (ws + 39424);    // 64*24*4  = 6144  -> 45568

  build_all<<<2, 64, 0, stream>>>(
      w, mu, sigma, erev, mask,
      sensory_w, sensory_mu, sensory_sigma, sensory_erev, sensory_mask,
      recP4, recP2, recAd, senP4, senP2, senAd, meta);

  const int B = in_sizes[0] / (TSTEPS * SDIM);
  ltc_run<<<B, 64, 0, stream>>>(
      obs, hidden, input_w, input_b, gleak, vleak, cm,
      q_w1, q_b1, q_w2, q_b2,
      recP4, recP2, recAd, senP4, senP2, senAd, meta,
      (float*)d_out, B);
}

// Round 3
// 519.725 us; speedup vs baseline: 1.2080x; 1.2080x over previous
//
#include <hip/hip_runtime.h>

#define UNITS   114
#define SDIM    64
#define ACT     18
#define TSTEPS  64

// Globally-balanced bin-packed slots (placement identical to R4..R8):
//   rec:     E <= 704 edges, max in-degree <= 32. C=13/lane, <=2 posts/lane,
//            <=3 lanes/post. sensory: E == 512, max in-degree <= 20. C=9.
#define CR 13
#define CS 9
#define ER_CAP 704
#define MSTRIDE 24

#define LOG2E 1.4426950408889634f
#define EPS   1e-8f

typedef float v2f __attribute__((ext_vector_type(2)));
__device__ __forceinline__ v2f fma2(v2f a, v2f b, v2f c) {
  return __builtin_elementwise_fma(a, b, c);
}
__device__ __forceinline__ float bperm(int addr, float v) {
  return __int_as_float(__builtin_amdgcn_ds_bpermute(addr, __float_as_int(v)));
}
__device__ __forceinline__ float dperm(int addr, float v) {   // push: lane[addr>>2] <- v
  return __int_as_float(__builtin_amdgcn_ds_permute(addr, __float_as_int(v)));
}
// Wave-internal LDS phase separator (compiler fence + wave barrier, ~0 instr).
__device__ __forceinline__ void wsync() {
  __builtin_amdgcn_fence(__ATOMIC_ACQ_REL, "wavefront");
  __builtin_amdgcn_wave_barrier();
}
__device__ __forceinline__ int canonLane(int u) { return (u >= 64) ? (u - 64) : u; }

// k-th set bit of a 64-bit mask (k 0-based).
__device__ __forceinline__ int kthSetBit(unsigned long long m, int k) {
  int pos = 0;
#pragma unroll
  for (int ww = 32; ww >= 1; ww >>= 1) {
    const unsigned long long lowMask = ((1ull << ww) - 1ull);
    const int c = __popcll(m & lowMask);
    if (k >= c) { k -= c; m >>= ww; pos += ww; }
  }
  return pos;
}

// ---------------------------------------------------------------------------
// Build: R12 = R11's bank-aware per-lane slot permutation, re-implemented as
// a register+ballot greedy (no LDS / no syncs in the loop). Same algorithm,
// same order, same tie-breaks -> bit-identical permutation to R11, at ~30 us
// instead of ~240 us (R11 paid a dependent-LDS round-trip per iteration).
//   - thread l holds the residue nibble-mask for candidate slot (l&15) in 4
//     scalar regs, replicated across the four 16-lane groups;
//   - argmin over 13 candidates via 5 ballots (cost levels) + ffsll;
//   - thread j records its own lane's permutation in regs, one LDS store.
// ---------------------------------------------------------------------------
__global__ __launch_bounds__(64) void build_all(
    const float* __restrict__ w,  const float* __restrict__ mu,
    const float* __restrict__ sigma, const float* __restrict__ erev,
    const float* __restrict__ mask,
    const float* __restrict__ sw, const float* __restrict__ smu,
    const float* __restrict__ ssg, const float* __restrict__ serev,
    const float* __restrict__ smask,
    float4* __restrict__ recP4, float2* __restrict__ recP2, int* __restrict__ recAd,
    float4* __restrict__ senP4, float2* __restrict__ senP2, int* __restrict__ senAd,
    int* __restrict__ meta)
{
  const int l = threadIdx.x;
  __shared__ short ePre[ER_CAP], ePIdx[ER_CAP];
  __shared__ int deg[64], off[65];
  __shared__ int pLane[64], pF0[64], pRole[64];
  __shared__ int contIdx[64], contOwn[64], splitRole[64], split2[64], ownP[128];
  __shared__ int rcv[64];
  __shared__ short laneAddr[64*CR];          // pre unit per (lane, origSlot); 0 = dummy
  __shared__ signed char permS[64*CR];       // newSlot per (lane, origSlot)

  contIdx[l] = 0; contOwn[l] = 0; splitRole[l] = -1; split2[l] = 0;
  ownP[2*l] = -1; ownP[2*l+1] = -1;
  pLane[l] = 0; pF0[l] = 0; pRole[l] = 0;

  if (blockIdx.x == 0) {
    int d = 0;
    if (l < 50) {
      for (int base = 18; base < 114; base += 16) {
        float mv[16];
#pragma unroll
        for (int q = 0; q < 16; ++q) mv[q] = mask[(base + q)*UNITS + l];
#pragma unroll
        for (int q = 0; q < 16; ++q) d += (mv[q] != 0.f) ? 1 : 0;
      }
    }
    deg[l] = (l < 50) ? d : 0;
    __syncthreads();
    if (l == 0) { int a = 0; for (int j = 0; j < 64; ++j) { off[j] = a; a += deg[j]; } off[64] = a; }
    __syncthreads();
    if (l < 50) {
      int o = off[l];
      for (int base = 18; base < 114; base += 16) {
        float mv[16];
#pragma unroll
        for (int q = 0; q < 16; ++q) mv[q] = mask[(base + q)*UNITS + l];
#pragma unroll
        for (int q = 0; q < 16; ++q)
          if (mv[q] != 0.f) { ePre[o] = (short)(base + q); ePIdx[o] = (short)l; ++o; }
      }
    }
    if (l == 0) {
      int lam = 0, f = 0, pc = 0;
      for (int p = 0; p < 50; ++p) {
        const int dd = deg[p];
        if (pc == 2 || f == CR || dd > 3*CR - f) { ++lam; f = 0; pc = 0; }
        if (lam > 63) lam = 63;
        pLane[p] = lam; pF0[p] = f; pRole[p] = pc;
        ownP[2*lam + pc] = p;
        const int owner = lam, role = pc; ++pc;
        const int take = dd < (CR - f) ? dd : (CR - f);
        f += take; int rem = dd - take;
        if (rem > 0) {
          splitRole[owner] = role; split2[owner] = (rem > CR) ? 1 : 0;
          ++lam; if (lam > 63) lam = 63; contIdx[lam] = 1; contOwn[lam] = owner; pc = 1;
          const int t2 = rem < CR ? rem : CR; f = t2; rem -= t2;
          if (rem > 0) { ++lam; if (lam > 63) lam = 63; contIdx[lam] = 2; contOwn[lam] = owner; pc = 1; f = rem; }
        }
      }
    }
    __syncthreads();
    int dA = (contIdx[l] == 1) ? contOwn[l] : -1;
    int dB = (contIdx[l] == 2) ? contOwn[l] : -1;
    rcv[l] = 0; __syncthreads();
    if (dA >= 0) rcv[dA] = 1;
    __syncthreads();
    { const unsigned long long rM = __ballot(rcv[l] != 0), dM = __ballot(dA < 0);
      if (dA < 0) dA = kthSetBit(~rM, __popcll(dM & ((1ull << l) - 1ull))); }
    __syncthreads();
    rcv[l] = 0; __syncthreads();
    if (dB >= 0) rcv[dB] = 1;
    __syncthreads();
    { const unsigned long long rM = __ballot(rcv[l] != 0), dM = __ballot(dB < 0);
      if (dB < 0) dB = kthSetBit(~rM, __popcll(dM & ((1ull << l) - 1ull))); }
    {
      int* M = meta + l * MSTRIDE;
      M[0] = dA * 4; M[1] = dB * 4;
      const float s1A = (splitRole[l] == 0) ? 1.f : 0.f, s1B = (splitRole[l] == 1) ? 1.f : 0.f;
      M[2] = __float_as_int(s1A); M[3] = __float_as_int(s1B);
      const float s2 = split2[l] ? 1.f : 0.f;
      M[4] = __float_as_int(s1A * s2); M[5] = __float_as_int(s1B * s2);
      const int uA = ownP[2*l], uB = ownP[2*l+1];
      M[6] = ((uA >= 0) ? uA : 128 + l) * 4;
      M[7] = ((uB >= 0) ? uB : 192 + l) * 4;
      M[8] = (uA >= 0) ? uA : 0;
      M[9] = (uB >= 0) ? uB : 0;
    }
    // ---- bank-aware slot permutation (R12: register+ballot greedy) ----
    for (int i = l; i < 64*CR; i += 64) laneAddr[i] = 0;
    __syncthreads();
    {
      const int E = off[64];
      for (int e = l; e < E; e += 64) {
        const int pj = ePIdx[e];
        const int r  = e - off[pj];
        const int dd = deg[pj], f0 = pF0[pj];
        const int take = dd < (CR - f0) ? dd : (CR - f0);
        int lane = pLane[pj], slot;
        if (r < take)            { slot = f0 + r; }
        else if (r < take + CR)  { lane += 1; slot = r - take; }
        else                     { lane += 2; slot = r - take - CR; }
        if (lane > 63) lane = 63;
        laneAddr[lane*CR + slot] = ePre[e];
      }
    }
    __syncthreads();
    {
      int av[CR];
#pragma unroll
      for (int os = 0; os < CR; ++os) av[os] = (int)laneAddr[l*CR + os];
      const int cs = l & 15;                 // replicated candidate slot
      unsigned bm0 = 0, bm1 = 0, bm2 = 0, bm3 = 0;  // nibble residue masks, 32 banks
      signed char myPerm[CR];
      for (int j = 0; j < 64; ++j) {
        int u[CR];
#pragma unroll
        for (int os = 0; os < CR; ++os) u[os] = __shfl(av[os], j);
        unsigned used = 0;
#pragma unroll
        for (int os = 0; os < CR; ++os) {
          const int bk = u[os] & 31, res = (u[os] >> 5) & 7;
          const int sh = (bk & 7) * 4;
          const unsigned bmsel = (bk < 8) ? bm0 : (bk < 16) ? bm1 : (bk < 24) ? bm2 : bm3;
          const int nib = (int)((bmsel >> sh) & 15u);
          const int have = (nib >> res) & 1;
          const int np = __popc((unsigned)(nib | (1 << res)));
          int level = 7;
          if (cs < CR && !(used & (1u << cs)))
            level = have ? 0 : ((np == 1) ? 1 : (np == 2) ? 2 : (np == 3) ? 3 : 4);
          const unsigned long long b0 = __ballot(level == 0);
          const unsigned long long b1 = __ballot(level == 1);
          const unsigned long long b2 = __ballot(level == 2);
          const unsigned long long b3 = __ballot(level == 3);
          const unsigned long long b4 = __ballot(level == 4);
          const unsigned long long sel = b0 ? b0 : b1 ? b1 : b2 ? b2 : b3 ? b3 : b4;
          const int ns = __ffsll(sel) - 1;   // lowest lane = lowest slot (tie-break)
          used |= 1u << ns;
          if (cs == ns) {                    // winner updates its replicated mask
            const unsigned add = ((unsigned)(1 << res)) << sh;
            if (bk < 8) bm0 |= add; else if (bk < 16) bm1 |= add;
            else if (bk < 24) bm2 |= add; else bm3 |= add;
          }
          myPerm[os] = (signed char)ns;
        }
        if (j == l) {
#pragma unroll
          for (int os = 0; os < CR; ++os) permS[l*CR + os] = myPerm[os];
        }
      }
    }
    __syncthreads();
    for (int t = l; t < CR*64; t += 64) {
      recP4[t] = make_float4(0.f,0.f,0.f,0.f); recP2[t] = make_float2(0.f,0.f); recAd[t] = 0;
    }
    __syncthreads();
    {
      const int E = off[64];
      for (int e = l; e < E; e += 64) {
        const int pre = ePre[e], pj = ePIdx[e];
        const int r  = e - off[pj];
        const int dd = deg[pj], f0 = pF0[pj], role0 = pRole[pj];
        const int take = dd < (CR - f0) ? dd : (CR - f0);
        int lane = pLane[pj], slot, role;
        if (r < take)            { slot = f0 + r;        role = role0; }
        else if (r < take + CR)  { lane += 1; slot = r - take;      role = 0; }
        else                     { lane += 2; slot = r - take - CR; role = 0; }
        if (lane > 63) lane = 63;
        const int idx = pre * UNITS + pj;
        const float sg = sigma[idx];
        const float nsgl = -sg * LOG2E, msl = mu[idx] * sg * LOG2E;
        const float wd = w[idx], wn = wd * erev[idx];
        const int tt = (int)permS[lane*CR + slot] * 64 + lane;   // permuted slot
        recP4[tt] = make_float4(nsgl, msl, role ? 0.f : wn, role ? 0.f : wd);
        recP2[tt] = role ? make_float2(wn, wd) : make_float2(0.f, 0.f);
        recAd[tt] = pre * 4;
      }
    }
  } else {
    int d = 0;
    {
      const int col = 50 + l;
      for (int base = 0; base < 64; base += 16) {
        float mv[16];
#pragma unroll
        for (int q = 0; q < 16; ++q) mv[q] = smask[(base + q)*UNITS + col];
#pragma unroll
        for (int q = 0; q < 16; ++q) d += (mv[q] != 0.f) ? 1 : 0;
      }
    }
    deg[l] = d;
    __syncthreads();
    if (l == 0) { int a = 0; for (int j = 0; j < 64; ++j) { off[j] = a; a += deg[j]; } off[64] = a; }
    __syncthreads();
    {
      int o = off[l]; const int col = 50 + l;
      for (int base = 0; base < 64; base += 16) {
        float mv[16];
#pragma unroll
        for (int q = 0; q < 16; ++q) mv[q] = smask[(base + q)*UNITS + col];
#pragma unroll
        for (int q = 0; q < 16; ++q)
          if (mv[q] != 0.f) { ePre[o] = (short)(base + q); ePIdx[o] = (short)l; ++o; }
      }
    }
    if (l == 0) {
      int lam = 0, f = 0, pc = 0;
      for (int p = 0; p < 64; ++p) {
        const int dd = deg[p];
        if (pc == 2 || f == CS || dd > 3*CS - f) { ++lam; f = 0; pc = 0; }
        if (lam > 63) lam = 63;
        pLane[p] = lam; pF0[p] = f; pRole[p] = pc;
        ownP[2*lam + pc] = p;
        const int owner = lam, role = pc; ++pc;
        const int take = dd < (CS - f) ? dd : (CS - f);
        f += take; int rem = dd - take;
        if (rem > 0) {
          splitRole[owner] = role; split2[owner] = (rem > CS) ? 1 : 0;
          ++lam; if (lam > 63) lam = 63; contIdx[lam] = 1; contOwn[lam] = owner; pc = 1;
          const int t2 = rem < CS ? rem : CS; f = t2; rem -= t2;
          if (rem > 0) { ++lam; if (lam > 63) lam = 63; contIdx[lam] = 2; contOwn[lam] = owner; pc = 1; f = rem; }
        }
      }
    }
    __syncthreads();
    int dA = (contIdx[l] == 1) ? contOwn[l] : -1;
    int dB = (contIdx[l] == 2) ? contOwn[l] : -1;
    rcv[l] = 0; __syncthreads();
    if (dA >= 0) rcv[dA] = 1;
    __syncthreads();
    { const unsigned long long rM = __ballot(rcv[l] != 0), dM = __ballot(dA < 0);
      if (dA < 0) dA = kthSetBit(~rM, __popcll(dM & ((1ull << l) - 1ull))); }
    __syncthreads();
    rcv[l] = 0; __syncthreads();
    if (dB >= 0) rcv[dB] = 1;
    __syncthreads();
    { const unsigned long long rM = __ballot(rcv[l] != 0), dM = __ballot(dB < 0);
      if (dB < 0) dB = kthSetBit(~rM, __popcll(dM & ((1ull << l) - 1ull))); }
    __syncthreads();
    int rA = (ownP[2*l]   >= 0) ? canonLane(50 + ownP[2*l])   : -1;
    int rB = (ownP[2*l+1] >= 0) ? canonLane(50 + ownP[2*l+1]) : -1;
    rcv[l] = 0; __syncthreads();
    if (rA >= 0) rcv[rA] = 1;
    __syncthreads();
    const int isRcvA = rcv[l];
    { const unsigned long long rM = __ballot(isRcvA != 0), dM = __ballot(rA < 0);
      if (rA < 0) rA = kthSetBit(~rM, __popcll(dM & ((1ull << l) - 1ull))); }
    __syncthreads();
    rcv[l] = 0; __syncthreads();
    if (rB >= 0) rcv[rB] = 1;
    __syncthreads();
    { const unsigned long long rM = __ballot(rcv[l] != 0), dM = __ballot(rB < 0);
      if (rB < 0) rB = kthSetBit(~rM, __popcll(dM & ((1ull << l) - 1ull))); }
    {
      int* M = meta + l * MSTRIDE;
      M[10] = dA * 4; M[11] = dB * 4;
      const float s1A = (splitRole[l] == 0) ? 1.f : 0.f, s1B = (splitRole[l] == 1) ? 1.f : 0.f;
      M[12] = __float_as_int(s1A); M[13] = __float_as_int(s1B);
      const float s2 = split2[l] ? 1.f : 0.f;
      M[14] = __float_as_int(s1A * s2); M[15] = __float_as_int(s1B * s2);
      M[16] = rA * 4; M[17] = rB * 4;
      M[18] = __float_as_int(isRcvA ? 1.f : 0.f);
      M[19] = __float_as_int(isRcvA ? 0.f : 1.f);
      const int pA = ownP[2*l], pB = ownP[2*l+1];
      M[20] = (pA >= 0) ? 50 + pA : 0;
      M[21] = (pB >= 0) ? 50 + pB : 0;
    }
    for (int t = l; t < CS*64; t += 64) {
      senP4[t] = make_float4(0.f,0.f,0.f,0.f); senP2[t] = make_float2(0.f,0.f); senAd[t] = 0;
    }
    __syncthreads();
    {
      const int E = off[64];
      for (int e = l; e < E; e += 64) {
        const int pre = ePre[e], pj = ePIdx[e];
        const int r  = e - off[pj];
        const int dd = deg[pj], f0 = pF0[pj], role0 = pRole[pj];
        const int take = dd < (CS - f0) ? dd : (CS - f0);
        int lane = pLane[pj], slot, role;
        if (r < take)            { slot = f0 + r;        role = role0; }
        else if (r < take + CS)  { lane += 1; slot = r - take;      role = 0; }
        else                     { lane += 2; slot = r - take - CS; role = 0; }
        if (lane > 63) lane = 63;
        const int col = 50 + pj;
        const int idx = pre * UNITS + col;
        const float sg = ssg[idx];
        const float nsgl = -sg * LOG2E, msl = smu[idx] * sg * LOG2E;
        const float wd = sw[idx], wn = wd * serev[idx];
        const int tt = slot * 64 + lane;
        senP4[tt] = make_float4(nsgl, msl, role ? 0.f : wn, role ? 0.f : wd);
        senP2[tt] = role ? make_float2(wn, wd) : make_float2(0.f, 0.f);
        senAd[tt] = pre * 4;
      }
    }
  }
}

// ---------------------------------------------------------------------------
// Run kernel: byte-identical to R10/R11 (no run-time cost for the bank fix;
// only the prebuilt slot layout changed).
// ---------------------------------------------------------------------------
__global__ __launch_bounds__(64, 2) void ltc_run(
    const float* __restrict__ obs,     const float* __restrict__ hidden,
    const float* __restrict__ input_w, const float* __restrict__ input_b,
    const float* __restrict__ gleak,   const float* __restrict__ vleak,
    const float* __restrict__ cm,
    const float* __restrict__ q_w1, const float* __restrict__ q_b1,
    const float* __restrict__ q_w2, const float* __restrict__ q_b2,
    const float4* __restrict__ recP4, const float2* __restrict__ recP2,
    const int* __restrict__ recAd,
    const float4* __restrict__ senP4, const float2* __restrict__ senP2,
    const int* __restrict__ senAd,
    const int* __restrict__ meta, float* __restrict__ out, int B)
{
  const int l = threadIdx.x, b = blockIdx.x;
  __shared__ float mirror[256];   // [0..113] units, [128..255] scratch sinks
  char* mbase = (char*)mirror;

  float rNS[CR], rMS[CR]; v2f rWA[CR], rWB[CR]; int rad[CR];
#pragma unroll
  for (int s = 0; s < CR; ++s) {
    const float4 p4 = recP4[s*64 + l]; const float2 p2 = recP2[s*64 + l];
    rNS[s] = p4.x; rMS[s] = p4.y; rWA[s] = (v2f){p4.z, p4.w};
    rWB[s] = (v2f){p2.x, p2.y}; rad[s] = recAd[s*64 + l];
  }
  float sNS[CS], sMS[CS]; v2f sWA[CS], sWB[CS]; int sad[CS];
#pragma unroll
  for (int s = 0; s < CS; ++s) {
    const float4 p4 = senP4[s*64 + l]; const float2 p2 = senP2[s*64 + l];
    sNS[s] = p4.x; sMS[s] = p4.y; sWA[s] = (v2f){p4.z, p4.w};
    sWB[s] = (v2f){p2.x, p2.y}; sad[s] = senAd[s*64 + l];
  }

  const int* M = meta + l * MSTRIDE;
  const int   rPush1 = M[0], rPush2 = M[1];
  const v2f gR1A = {__int_as_float(M[2]), __int_as_float(M[2])};
  const v2f gR1B = {__int_as_float(M[3]), __int_as_float(M[3])};
  const v2f gR2A = {__int_as_float(M[4]), __int_as_float(M[4])};
  const v2f gR2B = {__int_as_float(M[5]), __int_as_float(M[5])};
  const int   rWrA = M[6], rWrB = M[7], rUA = M[8], rUB = M[9];
  const int   sPush1 = M[10], sPush2 = M[11];
  const v2f gS1A = {__int_as_float(M[12]), __int_as_float(M[12])};
  const v2f gS1B = {__int_as_float(M[13]), __int_as_float(M[13])};
  const v2f gS2A = {__int_as_float(M[14]), __int_as_float(M[14])};
  const v2f gS2B = {__int_as_float(M[15]), __int_as_float(M[15])};
  const int   sRtA = M[16], sRtB = M[17];
  const float sRndA = __int_as_float(M[18]), sRndB = __int_as_float(M[19]);
  const int   sUA = M[20], sUB = M[21];

  const float cmA  = cm[rUA]*6.f, glvA  = gleak[rUA]*vleak[rUA], cgA  = cm[rUA]*6.f + gleak[rUA] + EPS;
  const float cmB  = cm[rUB]*6.f, glvB  = gleak[rUB]*vleak[rUB], cgB  = cm[rUB]*6.f + gleak[rUB] + EPS;
  const float cmSA = cm[sUA]*6.f, glvSA = gleak[sUA]*vleak[sUA], cgSA = cm[sUA]*6.f + gleak[sUA] + EPS;
  const float cmSB = cm[sUB]*6.f, glvSB = gleak[sUB]*vleak[sUB], cgSB = cm[sUB]*6.f + gleak[sUB] + EPS;

  // Ownership flags + folded accumulator inits (R10b).
  const bool ownA  = (rWrA < 512), ownB  = (rWrB < 512);
  const bool ownSA = (sUA != 0),   ownSB = (sUB != 0);
  const v2f initRA = ownA  ? (v2f){glvA,  cgA}  : (v2f){0.f, EPS};
  const v2f initRB = ownB  ? (v2f){glvB,  cgB}  : (v2f){0.f, EPS};
  const v2f initSA = ownSA ? (v2f){glvSA, cgSA} : (v2f){0.f, EPS};
  const v2f initSB = ownSB ? (v2f){glvSB, cgSB} : (v2f){0.f, EPS};

  const int  iUnit = (l < 50) ? 64 + l : l;
  const int  iWr   = iUnit * 4;
  float vIn = hidden[(size_t)b*UNITS + iUnit];
  float vPA = hidden[(size_t)b*UNITS + rUA];
  float vPB = hidden[(size_t)b*UNITS + rUB];

  mirror[l] = hidden[(size_t)b*UNITS + l];
  if (l < 50) mirror[64 + l] = hidden[(size_t)b*UNITS + 64 + l];

  const float iw = input_w[l], ibv = input_b[l];
  const float* ob = obs + (size_t)b*(TSTEPS*SDIM) + l;

  // ---- prologue: full sensory eval for t=0 ----
  float aI, bI;
  {
    const float xi = fmaf(ob[0], iw, ibv);
    float uu[CS];
#pragma unroll
    for (int s = 0; s < CS; ++s) {
      float z = fmaf(bperm(sad[s], xi), sNS[s], sMS[s]);
      z = fminf(z, 30.f);
      uu[s] = 1.f + __builtin_amdgcn_exp2f(z);
    }
    float sg[CS];
#pragma unroll
    for (int q = 0; q < 4; ++q) {
      const float p = uu[2*q] * uu[2*q+1];
      const float r = __builtin_amdgcn_rcpf(p);
      sg[2*q]   = uu[2*q+1] * r;
      sg[2*q+1] = uu[2*q]   * r;
    }
    sg[8] = __builtin_amdgcn_rcpf(uu[8]);
    v2f cA = {0.f,0.f}, cB = {0.f,0.f};
#pragma unroll
    for (int s = 0; s < CS; ++s) {
      const v2f s2 = {sg[s], sg[s]};
      cA = fma2(sWA[s], s2, cA);
      cB = fma2(sWB[s], s2, cB);
    }
    const v2f m1 = {dperm(sPush1, cA.x), dperm(sPush1, cA.y)};
    const v2f m2 = {dperm(sPush2, cA.x), dperm(sPush2, cA.y)};
    v2f tA = fma2(gS1A, m1, cA); tA = fma2(gS2A, m2, tA);
    v2f tB = fma2(gS1B, m1, cB); tB = fma2(gS2B, m2, tB);
    const float rdA = __builtin_amdgcn_rcpf(cgSA + tA.y);
    const float aA = cmSA * rdA, bA = (glvSA + tA.x) * rdA;
    const float rdB = __builtin_amdgcn_rcpf(cgSB + tB.y);
    const float aB = cmSB * rdB, bB = (glvSB + tB.x) * rdB;
    const float ra1 = dperm(sRtA, aA), rb1 = dperm(sRtA, bA);
    const float ra2 = dperm(sRtB, aB), rb2 = dperm(sRtB, bB);
    aI = sRndA*ra1 + sRndB*ra2;
    bI = sRndA*rb1 + sRndB*rb2;
  }

  // pipeline state for next-step sensory (accumulators carry folded consts)
  float xiN = fmaf(ob[SDIM], iw, ibv);   // xi(1)
  float xrC = ob[2*SDIM];                // obs(2)
  float su[CS];
  v2f acA = initSA, acB = initSB;
  v2f tSA = {0.f,0.f}, tSB = {0.f,0.f};
  float aIn = 0.f, bIn = 0.f;

  // one rec unfold with an embedded chunk of next-step sensory work
  auto unfold = [&](auto chunk) {
    wsync();
    float uu[CR];
#pragma unroll
    for (int s = 0; s < CR; ++s) {
      const float pv = *(const float*)(mbase + rad[s]);
      const float z = fmaf(pv, rNS[s], rMS[s]);   // z <= 20.8 always: no clamp
      uu[s] = 1.f + __builtin_amdgcn_exp2f(z);
    }
    chunk();                    // independent sensory work fills stalls here
    float sg[CR];
#pragma unroll
    for (int q = 0; q < 5; ++q) {
      const float p = uu[2*q] * uu[2*q+1];
      const float r = __builtin_amdgcn_rcpf(p);
      sg[2*q]   = uu[2*q+1] * r;
      sg[2*q+1] = uu[2*q]   * r;
    }
    {   // triple-shared rcp for slots 10,11,12
      const float p01 = uu[10]*uu[11];
      const float r = __builtin_amdgcn_rcpf(p01*uu[12]);
      const float t12 = uu[12]*r;
      sg[10] = uu[11]*t12; sg[11] = uu[10]*t12; sg[12] = p01*r;
    }
    v2f a0 = initRA, a1 = {0.f,0.f}, b0 = initRB, b1 = {0.f,0.f};
#pragma unroll
    for (int s = 0; s < CR; ++s) {
      const v2f s2 = {sg[s], sg[s]};
      if (s & 1) { a1 = fma2(rWA[s], s2, a1); b1 = fma2(rWB[s], s2, b1); }
      else       { a0 = fma2(rWA[s], s2, a0); b0 = fma2(rWB[s], s2, b0); }
    }
    v2f aA = a0 + a1, aB = b0 + b1;
    const v2f m1 = {dperm(rPush1, aA.x), dperm(rPush1, aA.y)};
    const v2f m2 = {dperm(rPush2, aA.x), dperm(rPush2, aA.y)};
    v2f tA = fma2(gR1A, m1, aA); tA = fma2(gR2A, m2, tA);
    v2f tB = fma2(gR1B, m1, aB); tB = fma2(gR2B, m2, tB);
    const float dAq = tA.y, dBq = tB.y;                   // consts pre-folded
    const float rr = __builtin_amdgcn_rcpf(dAq * dBq);    // paired rcp
    vPA = fmaf(cmA, vPA, tA.x) * (dBq * rr);
    vPB = fmaf(cmB, vPB, tB.x) * (dAq * rr);
    vIn = fmaf(aI, vIn, bI);
    wsync();
    *(float*)(mbase + rWrA) = vPA;
    *(float*)(mbase + rWrB) = vPB;
    *(float*)(mbase + iWr)  = vIn;
  };

  auto sExp = [&](int s) {
    float z = fmaf(bperm(sad[s], xiN), sNS[s], sMS[s]);
    z = fminf(z, 30.f);         // KEEP: sensory z can reach ~75 unclamped
    su[s] = 1.f + __builtin_amdgcn_exp2f(z);
  };
  auto sPair = [&](int s0) {
    const float p = su[s0] * su[s0+1];
    const float r = __builtin_amdgcn_rcpf(p);
    const float g0 = su[s0+1] * r, g1 = su[s0] * r;
    acA = fma2(sWA[s0],   (v2f){g0,g0}, acA);
    acA = fma2(sWA[s0+1], (v2f){g1,g1}, acA);
    acB = fma2(sWB[s0],   (v2f){g0,g0}, acB);
    acB = fma2(sWB[s0+1], (v2f){g1,g1}, acB);
  };

#pragma unroll 1
  for (int t = 0; t < TSTEPS; ++t) {
    unfold([&]{ sExp(0); sExp(1); });
    unfold([&]{ sExp(2); sExp(3); sPair(0); });
    unfold([&]{ sExp(4); sExp(5); sPair(2); });
    unfold([&]{ sExp(6); sExp(7); sExp(8); sPair(4); });
    unfold([&]{
      // triple-shared rcp for sensory slots 6,7,8 + accumulate + merge
      const float p67 = su[6] * su[7];
      const float r = __builtin_amdgcn_rcpf(p67 * su[8]);
      const float t67 = su[8] * r;
      const float g6 = su[7]*t67, g7 = su[6]*t67, g8 = p67*r;
      acA = fma2(sWA[6], (v2f){g6,g6}, acA); acB = fma2(sWB[6], (v2f){g6,g6}, acB);
      acA = fma2(sWA[7], (v2f){g7,g7}, acA); acB = fma2(sWB[7], (v2f){g7,g7}, acB);
      acA = fma2(sWA[8], (v2f){g8,g8}, acA); acB = fma2(sWB[8], (v2f){g8,g8}, acB);
      const v2f m1 = {dperm(sPush1, acA.x), dperm(sPush1, acA.y)};
      const v2f m2 = {dperm(sPush2, acA.x), dperm(sPush2, acA.y)};
      tSA = fma2(gS1A, m1, acA); tSA = fma2(gS2A, m2, tSA);
      tSB = fma2(gS1B, m1, acB); tSB = fma2(gS2B, m2, tSB);
    });
    unfold([&]{
      // route (aI,bI) for next step to canonical lanes (consts pre-folded)
      const float dA_ = tSA.y, dB_ = tSB.y;
      const float rr = __builtin_amdgcn_rcpf(dA_ * dB_);   // paired rcp
      const float rdA = dB_ * rr, rdB = dA_ * rr;
      const float aA = cmSA * rdA, bA = tSA.x * rdA;
      const float aB = cmSB * rdB, bB = tSB.x * rdB;
      const float ra1 = dperm(sRtA, aA), rb1 = dperm(sRtA, bA);
      const float ra2 = dperm(sRtB, aB), rb2 = dperm(sRtB, bB);
      aIn = sRndA*ra1 + sRndB*ra2;
      bIn = sRndA*rb1 + sRndB*rb2;
    });
    // step boundary: rotate pipeline state
    aI = aIn; bI = bIn;
    xiN = fmaf(xrC, iw, ibv);                      // xi(t+2)
    const int tn = (t + 3 < TSTEPS) ? (t + 3) : (TSTEPS - 1);
    xrC = ob[tn * SDIM];                           // obs(t+3), clamped
    acA = initSA; acB = initSB;
  }
  wsync();

  // ---- outputs: h then Q head ----
  float* __restrict__ outH = out + (size_t)B * ACT;
  outH[(size_t)b*UNITS + l] = mirror[l];
  if (l < 50) outH[(size_t)b*UNITS + 64 + l] = mirror[64 + l];

  const int j2 = (l < 50) ? 64 + l : l;
  float h1 = q_b1[l], h2 = q_b1[j2];
  for (int i = 0; i < UNITS; ++i) {
    const float hv = mirror[i];
    h1 = fmaf(hv, q_w1[i*UNITS + l],  h1);
    h2 = fmaf(hv, q_w1[i*UNITS + j2], h2);
  }
  h1 = fmaxf(h1, 0.f); h2 = fmaxf(h2, 0.f);
  wsync();
  mirror[l] = h1;
  if (l < 50) mirror[64 + l] = h2;
  wsync();
  if (l < ACT) {
    float q = q_b2[l];
    for (int i = 0; i < UNITS; ++i) q = fmaf(mirror[i], q_w2[i*ACT + l], q);
    out[(size_t)b*ACT + l] = q;
  }
}

extern "C" void kernel_launch(void* const* d_in, const int* in_sizes, int n_in,
                              void* d_out, int out_size, void* d_ws, size_t ws_size,
                              hipStream_t stream)
{
  const float* obs           = (const float*)d_in[0];
  const float* hidden        = (const float*)d_in[1];
  const float* input_w       = (const float*)d_in[2];
  const float* input_b       = (const float*)d_in[3];
  const float* sensory_w     = (const float*)d_in[4];
  const float* sensory_mu    = (const float*)d_in[5];
  const float* sensory_sigma = (const float*)d_in[6];
  const float* sensory_erev  = (const float*)d_in[7];
  const float* sensory_mask  = (const float*)d_in[8];
  const float* w             = (const float*)d_in[9];
  const float* mu            = (const float*)d_in[10];
  const float* sigma         = (const float*)d_in[11];
  const float* erev          = (const float*)d_in[12];
  const float* mask          = (const float*)d_in[13];
  const float* gleak         = (const float*)d_in[14];
  const float* vleak         = (const float*)d_in[15];
  const float* cm            = (const float*)d_in[16];
  const float* q_w1          = (const float*)d_in[17];
  const float* q_b1          = (const float*)d_in[18];
  const float* q_w2          = (const float*)d_in[19];
  const float* q_b2          = (const float*)d_in[20];

  char* ws = (char*)d_ws;
  float4* recP4 = (float4*)(ws);            // 13*64*16 = 13312
  float2* recP2 = (float2*)(ws + 13312);    // 13*64*8  = 6656  -> 19968
  int*    recAd = (int*)   (ws + 19968);    // 13*64*4  = 3328  -> 23296
  float4* senP4 = (float4*)(ws + 23296);    // 9*64*16  = 9216  -> 32512
  float2* senP2 = (float2*)(ws + 32512);    // 9*64*8   = 4608  -> 37120
  int*    senAd = (int*)   (ws + 37120);    // 9*64*4   = 2304  -> 39424
  int*    meta  = (int*)   (ws + 39424);    // 64*24*4  = 6144  -> 45568

  build_all<<<2, 64, 0, stream>>>(
      w, mu, sigma, erev, mask,
      sensory_w, sensory_mu, sensory_sigma, sensory_erev, sensory_mask,
      recP4, recP2, recAd, senP4, senP2, senAd, meta);

  const int B = in_sizes[0] / (TSTEPS * SDIM);
  ltc_run<<<B, 64, 0, stream>>>(
      obs, hidden, input_w, input_b, gleak, vleak, cm,
      q_w1, q_b1, q_w2, q_b2,
      recP4, recP2, recAd, senP4, senP2, senAd, meta,
      (float*)d_out, B);
}

// Round 4
// 388.381 us; speedup vs baseline: 1.6165x; 1.3382x over previous
//
#include <hip/hip_runtime.h>

#define UNITS   114
#define SDIM    64
#define ACT     18
#define TSTEPS  64

// Bin-packed slots (placement identical to R1/R4..R8):
//   rec: E <= 704 edges, C=13/lane, <=2 posts/lane, <=3 lanes/post.
//   sensory: E == 512, C=9.
#define CR 13
#define CS 9
#define ER_CAP 704

#define LOG2E 1.4426950408889634f
#define EPS   1e-8f

typedef float v2f __attribute__((ext_vector_type(2)));
__device__ __forceinline__ v2f fma2(v2f a, v2f b, v2f c) {
  return __builtin_elementwise_fma(a, b, c);
}
__device__ __forceinline__ float bperm(int addr, float v) {
  return __int_as_float(__builtin_amdgcn_ds_bpermute(addr, __float_as_int(v)));
}
__device__ __forceinline__ float dperm(int addr, float v) {   // push: lane[addr>>2] <- v
  return __int_as_float(__builtin_amdgcn_ds_permute(addr, __float_as_int(v)));
}
__device__ __forceinline__ void wsync() {
  __builtin_amdgcn_fence(__ATOMIC_ACQ_REL, "wavefront");
  __builtin_amdgcn_wave_barrier();
}
__device__ __forceinline__ int canonLane(int u) { return (u >= 64) ? (u - 64) : u; }

// k-th set bit of a 64-bit mask (k 0-based).
__device__ __forceinline__ int kthSetBit(unsigned long long m, int k) {
  int pos = 0;
#pragma unroll
  for (int ww = 32; ww >= 1; ww >>= 1) {
    const unsigned long long lowMask = ((1ull << ww) - 1ull);
    const int c = __popcll(m & lowMask);
    if (k >= c) { k -= c; m >>= ww; pos += ww; }
  }
  return pos;
}

// ---------------------------------------------------------------------------
// R13: fused kernel. Every block builds its own tables in-block (all blocks
// are co-resident, so the ~85us serial build+launch becomes a ~10-20us
// parallel prologue), then runs the proven R1 run loop (bit-identical
// layout/numerics; the R11/R12 slot permutation is REVERTED — R3 showed
// halved bank conflicts with zero run-time gain, so conflicts are off the
// critical path and the permutation was pure build cost).
// Key prologue pieces:
//  - greedy bin-pack: all-lane-redundant in registers (degrees via __shfl),
//    lane 0 mirrors per-post state to LDS. No LDS-dependent serial chain.
//  - table extraction: closed-form inverse of the forward (lane,slot) map
//    (continuation range / owner-A range / owner-B range are disjoint), so
//    all register arrays are written at compile-time slot indices.
// LDS ~5.5KB -> full co-residency preserved.
// ---------------------------------------------------------------------------
__global__ __launch_bounds__(64, 2) void ltc_fused(
    const float* __restrict__ obs,     const float* __restrict__ hidden,
    const float* __restrict__ input_w, const float* __restrict__ input_b,
    const float* __restrict__ sw, const float* __restrict__ smu,
    const float* __restrict__ ssg, const float* __restrict__ serev,
    const float* __restrict__ smask,
    const float* __restrict__ w, const float* __restrict__ mu,
    const float* __restrict__ sigma, const float* __restrict__ erev,
    const float* __restrict__ mask,
    const float* __restrict__ gleak, const float* __restrict__ vleak,
    const float* __restrict__ cm,
    const float* __restrict__ q_w1, const float* __restrict__ q_b1,
    const float* __restrict__ q_w2, const float* __restrict__ q_b2,
    float* __restrict__ out, int B)
{
  const int l = threadIdx.x, b = blockIdx.x;
  __shared__ float mirror[256];   // [0..113] units, [128..255] scratch sinks
  __shared__ short ePre[ER_CAP];
  __shared__ int offL[64], degL[64];
  __shared__ int pLane[64], pF0[64], pRole[64];
  __shared__ int contIdx[64], contOwn[64], splitRole[64], split2[64], ownP[128];
  __shared__ int rcv[64];
  char* mbase = (char*)mirror;

  // hoisted input staging (independent of tables)
  mirror[l] = hidden[(size_t)b*UNITS + l];
  if (l < 50) mirror[64 + l] = hidden[(size_t)b*UNITS + 64 + l];
  const float iw = input_w[l], ibv = input_b[l];
  const float* ob = obs + (size_t)b*(TSTEPS*SDIM) + l;

  // ===================== REC BUILD =====================
  int d = 0;
  if (l < 50) {
    for (int base = 18; base < 114; base += 16) {
      float mv[16];
#pragma unroll
      for (int q = 0; q < 16; ++q) mv[q] = mask[(base + q)*UNITS + l];
#pragma unroll
      for (int q = 0; q < 16; ++q) d += (mv[q] != 0.f) ? 1 : 0;
    }
  }
  const int dregR = (l < 50) ? d : 0;
  degL[l] = dregR;
  int incl = dregR;
#pragma unroll
  for (int o = 1; o < 64; o <<= 1) { const int nn = __shfl_up(incl, o); if (l >= o) incl += nn; }
  offL[l] = incl - dregR;
  contIdx[l] = 0; contOwn[l] = 0; splitRole[l] = -1; split2[l] = 0;
  ownP[2*l] = -1; ownP[2*l+1] = -1;
  wsync();
  if (l < 50) {
    int o = incl - dregR;
    for (int base = 18; base < 114; base += 16) {
      float mv[16];
#pragma unroll
      for (int q = 0; q < 16; ++q) mv[q] = mask[(base + q)*UNITS + l];
#pragma unroll
      for (int q = 0; q < 16; ++q)
        if (mv[q] != 0.f) ePre[o++] = (short)(base + q);
    }
  }
  wsync();
  {   // greedy bin-pack: all lanes redundant, l==0 mirrors to LDS
    int lam = 0, f = 0, pc = 0;
    for (int p = 0; p < 50; ++p) {
      const int dd = __shfl(dregR, p);
      if (pc == 2 || f == CR || dd > 3*CR - f) { ++lam; f = 0; pc = 0; }
      if (lam > 63) lam = 63;
      if (l == 0) { pLane[p] = lam; pF0[p] = f; pRole[p] = pc; ownP[2*lam + pc] = p; }
      const int owner = lam, role = pc; ++pc;
      const int take = dd < (CR - f) ? dd : (CR - f);
      f += take; int rem = dd - take;
      if (rem > 0) {
        if (l == 0) { splitRole[owner] = role; split2[owner] = (rem > CR) ? 1 : 0; }
        ++lam; if (lam > 63) lam = 63;
        if (l == 0) { contIdx[lam] = 1; contOwn[lam] = owner; }
        pc = 1;
        const int t2 = rem < CR ? rem : CR; f = t2; rem -= t2;
        if (rem > 0) {
          ++lam; if (lam > 63) lam = 63;
          if (l == 0) { contIdx[lam] = 2; contOwn[lam] = owner; }
          pc = 1; f = rem;
        }
      }
    }
  }
  wsync();
  // rec routing
  int dAr = (contIdx[l] == 1) ? contOwn[l] : -1;
  int dBr = (contIdx[l] == 2) ? contOwn[l] : -1;
  rcv[l] = 0; wsync();
  if (dAr >= 0) rcv[dAr] = 1;
  wsync();
  { const unsigned long long rM = __ballot(rcv[l] != 0), dM = __ballot(dAr < 0);
    if (dAr < 0) dAr = kthSetBit(~rM, __popcll(dM & ((1ull << l) - 1ull))); }
  wsync();
  rcv[l] = 0; wsync();
  if (dBr >= 0) rcv[dBr] = 1;
  wsync();
  { const unsigned long long rM = __ballot(rcv[l] != 0), dM = __ballot(dBr < 0);
    if (dBr < 0) dBr = kthSetBit(~rM, __popcll(dM & ((1ull << l) - 1ull))); }
  const int rPush1 = dAr * 4, rPush2 = dBr * 4;
  const float s1Ar = (splitRole[l] == 0) ? 1.f : 0.f, s1Br = (splitRole[l] == 1) ? 1.f : 0.f;
  const float s2r  = split2[l] ? 1.f : 0.f;
  const v2f gR1A = {s1Ar, s1Ar}, gR1B = {s1Br, s1Br};
  const v2f gR2A = {s1Ar*s2r, s1Ar*s2r}, gR2B = {s1Br*s2r, s1Br*s2r};
  const int uA = ownP[2*l], uB = ownP[2*l+1];
  const int rWrA = ((uA >= 0) ? uA : 128 + l) * 4;
  const int rWrB = ((uB >= 0) ? uB : 192 + l) * 4;
  const int rUA = (uA >= 0) ? uA : 0, rUB = (uB >= 0) ? uB : 0;
  // rec extraction (closed-form inverse of the forward (lane,slot) map)
  float rNS[CR], rMS[CR]; v2f rWA[CR], rWB[CR]; int rad[CR];
  {
    const int ci = contIdx[l];
    int p1 = -1, base1 = 0, cnt1 = 0;
    if (ci) {
      const int o = contOwn[l];
      p1 = ownP[2*o + splitRole[o]];
      const int br = (CR - pF0[p1]) + ((ci == 2) ? CR : 0);
      base1 = offL[p1] + br;
      cnt1 = degL[p1] - br; if (cnt1 > CR) cnt1 = CR;
    }
    int fA = 0, tA = -1, oAo = 0;
    if (uA >= 0) { fA = pF0[uA]; const int rm = CR - fA; const int dd = degL[uA];
                   tA = dd < rm ? dd : rm; oAo = offL[uA]; }
    int fB = 0, tB = -1, oBo = 0;
    if (uB >= 0) { fB = pF0[uB]; const int rm = CR - fB; const int dd = degL[uB];
                   tB = dd < rm ? dd : rm; oBo = offL[uB]; }
#pragma unroll
    for (int s = 0; s < CR; ++s) {
      int e = -1, post = 0, isB = 0;
      if (ci && s < cnt1)                          { e = base1 + s;      post = p1; }
      else if (uA >= 0 && s >= fA && s < fA + tA)  { e = oAo + (s - fA); post = uA; }
      else if (uB >= 0 && s >= fB && s < fB + tB)  { e = oBo + (s - fB); post = uB; isB = 1; }
      if (e >= 0) {
        const int pre = (int)ePre[e];
        const int idx = pre * UNITS + post;
        const float sg_ = sigma[idx];
        rNS[s] = -sg_ * LOG2E; rMS[s] = mu[idx] * sg_ * LOG2E;
        const float wd = w[idx], wn = wd * erev[idx];
        rWA[s] = isB ? (v2f){0.f, 0.f} : (v2f){wn, wd};
        rWB[s] = isB ? (v2f){wn, wd} : (v2f){0.f, 0.f};
        rad[s] = pre * 4;
      } else {
        rNS[s] = 0.f; rMS[s] = 0.f;
        rWA[s] = (v2f){0.f, 0.f}; rWB[s] = (v2f){0.f, 0.f};
        rad[s] = 0;
      }
    }
  }
  wsync();   // rec done reading build LDS before sensory overwrites

  // ===================== SENSORY BUILD =====================
  int ds_ = 0;
  {
    const int col = 50 + l;
    for (int base = 0; base < 64; base += 16) {
      float mv[16];
#pragma unroll
      for (int q = 0; q < 16; ++q) mv[q] = smask[(base + q)*UNITS + col];
#pragma unroll
      for (int q = 0; q < 16; ++q) ds_ += (mv[q] != 0.f) ? 1 : 0;
    }
  }
  const int dregS = ds_;
  degL[l] = dregS;
  int inclS = dregS;
#pragma unroll
  for (int o = 1; o < 64; o <<= 1) { const int nn = __shfl_up(inclS, o); if (l >= o) inclS += nn; }
  offL[l] = inclS - dregS;
  contIdx[l] = 0; contOwn[l] = 0; splitRole[l] = -1; split2[l] = 0;
  ownP[2*l] = -1; ownP[2*l+1] = -1;
  wsync();
  {
    int o = inclS - dregS; const int col = 50 + l;
    for (int base = 0; base < 64; base += 16) {
      float mv[16];
#pragma unroll
      for (int q = 0; q < 16; ++q) mv[q] = smask[(base + q)*UNITS + col];
#pragma unroll
      for (int q = 0; q < 16; ++q)
        if (mv[q] != 0.f) ePre[o++] = (short)(base + q);
    }
  }
  wsync();
  {   // greedy bin-pack (sensory): NP=64, C=CS
    int lam = 0, f = 0, pc = 0;
    for (int p = 0; p < 64; ++p) {
      const int dd = __shfl(dregS, p);
      if (pc == 2 || f == CS || dd > 3*CS - f) { ++lam; f = 0; pc = 0; }
      if (lam > 63) lam = 63;
      if (l == 0) { pLane[p] = lam; pF0[p] = f; pRole[p] = pc; ownP[2*lam + pc] = p; }
      const int owner = lam, role = pc; ++pc;
      const int take = dd < (CS - f) ? dd : (CS - f);
      f += take; int rem = dd - take;
      if (rem > 0) {
        if (l == 0) { splitRole[owner] = role; split2[owner] = (rem > CS) ? 1 : 0; }
        ++lam; if (lam > 63) lam = 63;
        if (l == 0) { contIdx[lam] = 1; contOwn[lam] = owner; }
        pc = 1;
        const int t2 = rem < CS ? rem : CS; f = t2; rem -= t2;
        if (rem > 0) {
          ++lam; if (lam > 63) lam = 63;
          if (l == 0) { contIdx[lam] = 2; contOwn[lam] = owner; }
          pc = 1; f = rem;
        }
      }
    }
  }
  wsync();
  // sensory routing: partial-accumulator pushes
  int dAs = (contIdx[l] == 1) ? contOwn[l] : -1;
  int dBs = (contIdx[l] == 2) ? contOwn[l] : -1;
  rcv[l] = 0; wsync();
  if (dAs >= 0) rcv[dAs] = 1;
  wsync();
  { const unsigned long long rM = __ballot(rcv[l] != 0), dM = __ballot(dAs < 0);
    if (dAs < 0) dAs = kthSetBit(~rM, __popcll(dM & ((1ull << l) - 1ull))); }
  wsync();
  rcv[l] = 0; wsync();
  if (dBs >= 0) rcv[dBs] = 1;
  wsync();
  { const unsigned long long rM = __ballot(rcv[l] != 0), dM = __ballot(dBs < 0);
    if (dBs < 0) dBs = kthSetBit(~rM, __popcll(dM & ((1ull << l) - 1ull))); }
  wsync();
  // sensory routing: (a,b) route to canonical lanes
  int rAs = (ownP[2*l]   >= 0) ? canonLane(50 + ownP[2*l])   : -1;
  int rBs = (ownP[2*l+1] >= 0) ? canonLane(50 + ownP[2*l+1]) : -1;
  rcv[l] = 0; wsync();
  if (rAs >= 0) rcv[rAs] = 1;
  wsync();
  const int isRcvA = rcv[l];
  { const unsigned long long rM = __ballot(isRcvA != 0), dM = __ballot(rAs < 0);
    if (rAs < 0) rAs = kthSetBit(~rM, __popcll(dM & ((1ull << l) - 1ull))); }
  wsync();
  rcv[l] = 0; wsync();
  if (rBs >= 0) rcv[rBs] = 1;
  wsync();
  { const unsigned long long rM = __ballot(rcv[l] != 0), dM = __ballot(rBs < 0);
    if (rBs < 0) rBs = kthSetBit(~rM, __popcll(dM & ((1ull << l) - 1ull))); }
  const int sPush1 = dAs * 4, sPush2 = dBs * 4;
  const float s1As = (splitRole[l] == 0) ? 1.f : 0.f, s1Bs = (splitRole[l] == 1) ? 1.f : 0.f;
  const float s2s  = split2[l] ? 1.f : 0.f;
  const v2f gS1A = {s1As, s1As}, gS1B = {s1Bs, s1Bs};
  const v2f gS2A = {s1As*s2s, s1As*s2s}, gS2B = {s1Bs*s2s, s1Bs*s2s};
  const int sRtA = rAs * 4, sRtB = rBs * 4;
  const float sRndA = isRcvA ? 1.f : 0.f, sRndB = isRcvA ? 0.f : 1.f;
  const int pAs = ownP[2*l], pBs = ownP[2*l+1];
  const int sUA = (pAs >= 0) ? 50 + pAs : 0;
  const int sUB = (pBs >= 0) ? 50 + pBs : 0;
  // sensory extraction
  float sNS[CS], sMS[CS]; v2f sWA[CS], sWB[CS]; int sad[CS];
  {
    const int ci = contIdx[l];
    int p1 = -1, base1 = 0, cnt1 = 0;
    if (ci) {
      const int o = contOwn[l];
      p1 = ownP[2*o + splitRole[o]];
      const int br = (CS - pF0[p1]) + ((ci == 2) ? CS : 0);
      base1 = offL[p1] + br;
      cnt1 = degL[p1] - br; if (cnt1 > CS) cnt1 = CS;
    }
    int fA = 0, tA = -1, oAo = 0;
    if (pAs >= 0) { fA = pF0[pAs]; const int rm = CS - fA; const int dd = degL[pAs];
                    tA = dd < rm ? dd : rm; oAo = offL[pAs]; }
    int fB = 0, tB = -1, oBo = 0;
    if (pBs >= 0) { fB = pF0[pBs]; const int rm = CS - fB; const int dd = degL[pBs];
                    tB = dd < rm ? dd : rm; oBo = offL[pBs]; }
#pragma unroll
    for (int s = 0; s < CS; ++s) {
      int e = -1, post = 0, isB = 0;
      if (ci && s < cnt1)                           { e = base1 + s;      post = p1;  }
      else if (pAs >= 0 && s >= fA && s < fA + tA)  { e = oAo + (s - fA); post = pAs; }
      else if (pBs >= 0 && s >= fB && s < fB + tB)  { e = oBo + (s - fB); post = pBs; isB = 1; }
      if (e >= 0) {
        const int pre = (int)ePre[e];
        const int idx = pre * UNITS + 50 + post;
        const float sg_ = ssg[idx];
        sNS[s] = -sg_ * LOG2E; sMS[s] = smu[idx] * sg_ * LOG2E;
        const float wd = sw[idx], wn = wd * serev[idx];
        sWA[s] = isB ? (v2f){0.f, 0.f} : (v2f){wn, wd};
        sWB[s] = isB ? (v2f){wn, wd} : (v2f){0.f, 0.f};
        sad[s] = pre * 4;
      } else {
        sNS[s] = 0.f; sMS[s] = 0.f;
        sWA[s] = (v2f){0.f, 0.f}; sWB[s] = (v2f){0.f, 0.f};
        sad[s] = 0;
      }
    }
  }

  // ===================== RUN (identical to R1) =====================
  const float cmA  = cm[rUA]*6.f, glvA  = gleak[rUA]*vleak[rUA], cgA  = cm[rUA]*6.f + gleak[rUA] + EPS;
  const float cmB  = cm[rUB]*6.f, glvB  = gleak[rUB]*vleak[rUB], cgB  = cm[rUB]*6.f + gleak[rUB] + EPS;
  const float cmSA = cm[sUA]*6.f, glvSA = gleak[sUA]*vleak[sUA], cgSA = cm[sUA]*6.f + gleak[sUA] + EPS;
  const float cmSB = cm[sUB]*6.f, glvSB = gleak[sUB]*vleak[sUB], cgSB = cm[sUB]*6.f + gleak[sUB] + EPS;

  const bool ownA  = (rWrA < 512), ownB  = (rWrB < 512);
  const bool ownSA = (sUA != 0),   ownSB = (sUB != 0);
  const v2f initRA = ownA  ? (v2f){glvA,  cgA}  : (v2f){0.f, EPS};
  const v2f initRB = ownB  ? (v2f){glvB,  cgB}  : (v2f){0.f, EPS};
  const v2f initSA = ownSA ? (v2f){glvSA, cgSA} : (v2f){0.f, EPS};
  const v2f initSB = ownSB ? (v2f){glvSB, cgSB} : (v2f){0.f, EPS};

  const int  iUnit = (l < 50) ? 64 + l : l;
  const int  iWr   = iUnit * 4;
  float vIn = hidden[(size_t)b*UNITS + iUnit];
  float vPA = hidden[(size_t)b*UNITS + rUA];
  float vPB = hidden[(size_t)b*UNITS + rUB];

  // ---- prologue: full sensory eval for t=0 ----
  float aI, bI;
  {
    const float xi = fmaf(ob[0], iw, ibv);
    float uu[CS];
#pragma unroll
    for (int s = 0; s < CS; ++s) {
      float z = fmaf(bperm(sad[s], xi), sNS[s], sMS[s]);
      z = fminf(z, 30.f);
      uu[s] = 1.f + __builtin_amdgcn_exp2f(z);
    }
    float sg[CS];
#pragma unroll
    for (int q = 0; q < 4; ++q) {
      const float p = uu[2*q] * uu[2*q+1];
      const float r = __builtin_amdgcn_rcpf(p);
      sg[2*q]   = uu[2*q+1] * r;
      sg[2*q+1] = uu[2*q]   * r;
    }
    sg[8] = __builtin_amdgcn_rcpf(uu[8]);
    v2f cA = {0.f,0.f}, cB = {0.f,0.f};
#pragma unroll
    for (int s = 0; s < CS; ++s) {
      const v2f s2 = {sg[s], sg[s]};
      cA = fma2(sWA[s], s2, cA);
      cB = fma2(sWB[s], s2, cB);
    }
    const v2f m1 = {dperm(sPush1, cA.x), dperm(sPush1, cA.y)};
    const v2f m2 = {dperm(sPush2, cA.x), dperm(sPush2, cA.y)};
    v2f tA = fma2(gS1A, m1, cA); tA = fma2(gS2A, m2, tA);
    v2f tB = fma2(gS1B, m1, cB); tB = fma2(gS2B, m2, tB);
    const float rdA = __builtin_amdgcn_rcpf(cgSA + tA.y);
    const float aA = cmSA * rdA, bA = (glvSA + tA.x) * rdA;
    const float rdB = __builtin_amdgcn_rcpf(cgSB + tB.y);
    const float aB = cmSB * rdB, bB = (glvSB + tB.x) * rdB;
    const float ra1 = dperm(sRtA, aA), rb1 = dperm(sRtA, bA);
    const float ra2 = dperm(sRtB, aB), rb2 = dperm(sRtB, bB);
    aI = sRndA*ra1 + sRndB*ra2;
    bI = sRndA*rb1 + sRndB*rb2;
  }

  float xiN = fmaf(ob[SDIM], iw, ibv);   // xi(1)
  float xrC = ob[2*SDIM];                // obs(2)
  float su[CS];
  v2f acA = initSA, acB = initSB;
  v2f tSA = {0.f,0.f}, tSB = {0.f,0.f};
  float aIn = 0.f, bIn = 0.f;

  auto unfold = [&](auto chunk) {
    wsync();
    float uu[CR];
#pragma unroll
    for (int s = 0; s < CR; ++s) {
      const float pv = *(const float*)(mbase + rad[s]);
      const float z = fmaf(pv, rNS[s], rMS[s]);   // z <= 20.8 always: no clamp
      uu[s] = 1.f + __builtin_amdgcn_exp2f(z);
    }
    chunk();
    float sg[CR];
#pragma unroll
    for (int q = 0; q < 5; ++q) {
      const float p = uu[2*q] * uu[2*q+1];
      const float r = __builtin_amdgcn_rcpf(p);
      sg[2*q]   = uu[2*q+1] * r;
      sg[2*q+1] = uu[2*q]   * r;
    }
    {   // triple-shared rcp for slots 10,11,12
      const float p01 = uu[10]*uu[11];
      const float r = __builtin_amdgcn_rcpf(p01*uu[12]);
      const float t12 = uu[12]*r;
      sg[10] = uu[11]*t12; sg[11] = uu[10]*t12; sg[12] = p01*r;
    }
    v2f a0 = initRA, a1 = {0.f,0.f}, b0 = initRB, b1 = {0.f,0.f};
#pragma unroll
    for (int s = 0; s < CR; ++s) {
      const v2f s2 = {sg[s], sg[s]};
      if (s & 1) { a1 = fma2(rWA[s], s2, a1); b1 = fma2(rWB[s], s2, b1); }
      else       { a0 = fma2(rWA[s], s2, a0); b0 = fma2(rWB[s], s2, b0); }
    }
    v2f aA = a0 + a1, aB = b0 + b1;
    const v2f m1 = {dperm(rPush1, aA.x), dperm(rPush1, aA.y)};
    const v2f m2 = {dperm(rPush2, aA.x), dperm(rPush2, aA.y)};
    v2f tA = fma2(gR1A, m1, aA); tA = fma2(gR2A, m2, tA);
    v2f tB = fma2(gR1B, m1, aB); tB = fma2(gR2B, m2, tB);
    const float dAq = tA.y, dBq = tB.y;
    const float rr = __builtin_amdgcn_rcpf(dAq * dBq);
    vPA = fmaf(cmA, vPA, tA.x) * (dBq * rr);
    vPB = fmaf(cmB, vPB, tB.x) * (dAq * rr);
    vIn = fmaf(aI, vIn, bI);
    wsync();
    *(float*)(mbase + rWrA) = vPA;
    *(float*)(mbase + rWrB) = vPB;
    *(float*)(mbase + iWr)  = vIn;
  };

  auto sExp = [&](int s) {
    float z = fmaf(bperm(sad[s], xiN), sNS[s], sMS[s]);
    z = fminf(z, 30.f);         // KEEP: sensory z can reach ~75 unclamped
    su[s] = 1.f + __builtin_amdgcn_exp2f(z);
  };
  auto sPair = [&](int s0) {
    const float p = su[s0] * su[s0+1];
    const float r = __builtin_amdgcn_rcpf(p);
    const float g0 = su[s0+1] * r, g1 = su[s0] * r;
    acA = fma2(sWA[s0],   (v2f){g0,g0}, acA);
    acA = fma2(sWA[s0+1], (v2f){g1,g1}, acA);
    acB = fma2(sWB[s0],   (v2f){g0,g0}, acB);
    acB = fma2(sWB[s0+1], (v2f){g1,g1}, acB);
  };

#pragma unroll 1
  for (int t = 0; t < TSTEPS; ++t) {
    unfold([&]{ sExp(0); sExp(1); });
    unfold([&]{ sExp(2); sExp(3); sPair(0); });
    unfold([&]{ sExp(4); sExp(5); sPair(2); });
    unfold([&]{ sExp(6); sExp(7); sExp(8); sPair(4); });
    unfold([&]{
      const float p67 = su[6] * su[7];
      const float r = __builtin_amdgcn_rcpf(p67 * su[8]);
      const float t67 = su[8] * r;
      const float g6 = su[7]*t67, g7 = su[6]*t67, g8 = p67*r;
      acA = fma2(sWA[6], (v2f){g6,g6}, acA); acB = fma2(sWB[6], (v2f){g6,g6}, acB);
      acA = fma2(sWA[7], (v2f){g7,g7}, acA); acB = fma2(sWB[7], (v2f){g7,g7}, acB);
      acA = fma2(sWA[8], (v2f){g8,g8}, acA); acB = fma2(sWB[8], (v2f){g8,g8}, acB);
      const v2f m1 = {dperm(sPush1, acA.x), dperm(sPush1, acA.y)};
      const v2f m2 = {dperm(sPush2, acA.x), dperm(sPush2, acA.y)};
      tSA = fma2(gS1A, m1, acA); tSA = fma2(gS2A, m2, tSA);
      tSB = fma2(gS1B, m1, acB); tSB = fma2(gS2B, m2, tSB);
    });
    unfold([&]{
      const float dA_ = tSA.y, dB_ = tSB.y;
      const float rr = __builtin_amdgcn_rcpf(dA_ * dB_);
      const float rdA = dB_ * rr, rdB = dA_ * rr;
      const float aA = cmSA * rdA, bA = tSA.x * rdA;
      const float aB = cmSB * rdB, bB = tSB.x * rdB;
      const float ra1 = dperm(sRtA, aA), rb1 = dperm(sRtA, bA);
      const float ra2 = dperm(sRtB, aB), rb2 = dperm(sRtB, bB);
      aIn = sRndA*ra1 + sRndB*ra2;
      bIn = sRndA*rb1 + sRndB*rb2;
    });
    aI = aIn; bI = bIn;
    xiN = fmaf(xrC, iw, ibv);                      // xi(t+2)
    const int tn = (t + 3 < TSTEPS) ? (t + 3) : (TSTEPS - 1);
    xrC = ob[tn * SDIM];                           // obs(t+3), clamped
    acA = initSA; acB = initSB;
  }
  wsync();

  // ---- outputs: h then Q head ----
  float* __restrict__ outH = out + (size_t)B * ACT;
  outH[(size_t)b*UNITS + l] = mirror[l];
  if (l < 50) outH[(size_t)b*UNITS + 64 + l] = mirror[64 + l];

  const int j2 = (l < 50) ? 64 + l : l;
  float h1 = q_b1[l], h2 = q_b1[j2];
  for (int i = 0; i < UNITS; ++i) {
    const float hv = mirror[i];
    h1 = fmaf(hv, q_w1[i*UNITS + l],  h1);
    h2 = fmaf(hv, q_w1[i*UNITS + j2], h2);
  }
  h1 = fmaxf(h1, 0.f); h2 = fmaxf(h2, 0.f);
  wsync();
  mirror[l] = h1;
  if (l < 50) mirror[64 + l] = h2;
  wsync();
  if (l < ACT) {
    float q = q_b2[l];
    for (int i = 0; i < UNITS; ++i) q = fmaf(mirror[i], q_w2[i*ACT + l], q);
    out[(size_t)b*ACT + l] = q;
  }
}

extern "C" void kernel_launch(void* const* d_in, const int* in_sizes, int n_in,
                              void* d_out, int out_size, void* d_ws, size_t ws_size,
                              hipStream_t stream)
{
  const float* obs           = (const float*)d_in[0];
  const float* hidden        = (const float*)d_in[1];
  const float* input_w       = (const float*)d_in[2];
  const float* input_b       = (const float*)d_in[3];
  const float* sensory_w     = (const float*)d_in[4];
  const float* sensory_mu    = (const float*)d_in[5];
  const float* sensory_sigma = (const float*)d_in[6];
  const float* sensory_erev  = (const float*)d_in[7];
  const float* sensory_mask  = (const float*)d_in[8];
  const float* w             = (const float*)d_in[9];
  const float* mu            = (const float*)d_in[10];
  const float* sigma         = (const float*)d_in[11];
  const float* erev          = (const float*)d_in[12];
  const float* mask          = (const float*)d_in[13];
  const float* gleak         = (const float*)d_in[14];
  const float* vleak         = (const float*)d_in[15];
  const float* cm            = (const float*)d_in[16];
  const float* q_w1          = (const float*)d_in[17];
  const float* q_b1          = (const float*)d_in[18];
  const float* q_w2          = (const float*)d_in[19];
  const float* q_b2          = (const float*)d_in[20];

  const int B = in_sizes[0] / (TSTEPS * SDIM);
  ltc_fused<<<B, 64, 0, stream>>>(
      obs, hidden, input_w, input_b,
      sensory_w, sensory_mu, sensory_sigma, sensory_erev, sensory_mask,
      w, mu, sigma, erev, mask,
      gleak, vleak, cm,
      q_w1, q_b1, q_w2, q_b2,
      (float*)d_out, B);
}

// Round 5
// 359.346 us; speedup vs baseline: 1.7471x; 1.0808x over previous
//
#include <hip/hip_runtime.h>

#define UNITS   114
#define SDIM    64
#define ACT     18
#define TSTEPS  64

// Bin-packed slots (placement identical to R1):
//   rec: E <= 704 edges, C=13/lane, <=2 posts/lane, <=3 lanes/post.
//   sensory: E == 512, C=9.
#define CR 13
#define CS 9
#define MSTRIDE 24

#define LOG2E 1.4426950408889634f
#define EPS   1e-8f

typedef float v2f __attribute__((ext_vector_type(2)));
__device__ __forceinline__ v2f fma2(v2f a, v2f b, v2f c) {
  return __builtin_elementwise_fma(a, b, c);
}
__device__ __forceinline__ float bperm(int addr, float v) {
  return __int_as_float(__builtin_amdgcn_ds_bpermute(addr, __float_as_int(v)));
}
__device__ __forceinline__ float dperm(int addr, float v) {   // push: lane[addr>>2] <- v
  return __int_as_float(__builtin_amdgcn_ds_permute(addr, __float_as_int(v)));
}
__device__ __forceinline__ void wsync() {
  __builtin_amdgcn_fence(__ATOMIC_ACQ_REL, "wavefront");
  __builtin_amdgcn_wave_barrier();
}
__device__ __forceinline__ int canonLane(int u) { return (u >= 64) ? (u - 64) : u; }

// k-th set bit of a 64-bit mask (k 0-based).
__device__ __forceinline__ int kthSetBit(unsigned long long m, int k) {
  int pos = 0;
#pragma unroll
  for (int ww = 32; ww >= 1; ww >>= 1) {
    const unsigned long long lowMask = ((1ull << ww) - 1ull);
    const int c = __popcll(m & lowMask);
    if (k >= c) { k -= c; m >>= ww; pos += ww; }
  }
  return pos;
}
__device__ __forceinline__ unsigned long long shfl_u64(unsigned long long v, int src) {
  const int lo = __shfl((int)(unsigned)(v & 0xffffffffull), src);
  const int hi = __shfl((int)(unsigned)(v >> 32), src);
  return ((unsigned long long)(unsigned)hi << 32) | (unsigned)lo;
}

// ---------------------------------------------------------------------------
// R14 build: 8 parallel blocks (0..3 rec, 4..7 sensory). Each block:
//  - 1-pass mask scan -> per-lane column BITMASK in registers (no ePre, no
//    second pass, no offset scan);
//  - register+shfl greedy bin-pack (validated in R4) with l==0 mirroring the
//    small per-post state to LDS;
//  - ballot routing (validated);
//  - closed-form (lane,slot)->(post,rank) inverse (validated in R4), with
//    pre = kthSetBit(colmask(post), rank); slots sliced s%4==bid across the
//    4 blocks of each family. Tables bit-identical to R1's build.
// ---------------------------------------------------------------------------
__global__ __launch_bounds__(64) void build_all(
    const float* __restrict__ w,  const float* __restrict__ mu,
    const float* __restrict__ sigma, const float* __restrict__ erev,
    const float* __restrict__ mask,
    const float* __restrict__ sw, const float* __restrict__ smu,
    const float* __restrict__ ssg, const float* __restrict__ serev,
    const float* __restrict__ smask,
    float4* __restrict__ recP4, float2* __restrict__ recP2, int* __restrict__ recAd,
    float4* __restrict__ senP4, float2* __restrict__ senP2, int* __restrict__ senAd,
    int* __restrict__ meta)
{
  const int l = threadIdx.x;
  const int bid = blockIdx.x;
  __shared__ int degL[64], pF0L[64];
  __shared__ int contIdx[64], contOwn[64], splitRole[64], split2[64], ownP[128];
  __shared__ int rcv[64];

  contIdx[l] = 0; contOwn[l] = 0; splitRole[l] = -1; split2[l] = 0;
  ownP[2*l] = -1; ownP[2*l+1] = -1;

  if (bid < 4) {
    // ================= REC family =================
    // 1-pass column bitmask: lane l owns post-column l (l<50); pres 18..113.
    unsigned long long cLo = 0ull, cHi = 0ull;   // cLo bit r: pre 18+r; cHi bit r: pre 82+r
    if (l < 50) {
      for (int base = 0; base < 64; base += 16) {
        float mv[16];
#pragma unroll
        for (int q = 0; q < 16; ++q) mv[q] = mask[(18 + base + q)*UNITS + l];
#pragma unroll
        for (int q = 0; q < 16; ++q) if (mv[q] != 0.f) cLo |= (1ull << (base + q));
      }
      for (int base = 0; base < 32; base += 16) {
        float mv[16];
#pragma unroll
        for (int q = 0; q < 16; ++q) mv[q] = mask[(82 + base + q)*UNITS + l];
#pragma unroll
        for (int q = 0; q < 16; ++q) if (mv[q] != 0.f) cHi |= (1ull << (base + q));
      }
    }
    const int dreg = __popcll(cLo) + __popcll(cHi);
    degL[l] = dreg;
    wsync();
    {   // greedy bin-pack (all lanes redundant; l==0 mirrors to LDS)
      int lam = 0, f = 0, pc = 0;
      for (int p = 0; p < 50; ++p) {
        const int dd = __shfl(dreg, p);
        if (pc == 2 || f == CR || dd > 3*CR - f) { ++lam; f = 0; pc = 0; }
        if (lam > 63) lam = 63;
        if (l == 0) { pF0L[p] = f; ownP[2*lam + pc] = p; }
        const int owner = lam, role = pc; ++pc;
        const int take = dd < (CR - f) ? dd : (CR - f);
        f += take; int rem = dd - take;
        if (rem > 0) {
          if (l == 0) { splitRole[owner] = role; split2[owner] = (rem > CR) ? 1 : 0; }
          ++lam; if (lam > 63) lam = 63;
          if (l == 0) { contIdx[lam] = 1; contOwn[lam] = owner; }
          pc = 1;
          const int t2 = rem < CR ? rem : CR; f = t2; rem -= t2;
          if (rem > 0) {
            ++lam; if (lam > 63) lam = 63;
            if (l == 0) { contIdx[lam] = 2; contOwn[lam] = owner; }
            pc = 1; f = rem;
          }
        }
      }
    }
    wsync();
    // routing (push targets for partial accumulators)
    int dAr = (contIdx[l] == 1) ? contOwn[l] : -1;
    int dBr = (contIdx[l] == 2) ? contOwn[l] : -1;
    rcv[l] = 0; wsync();
    if (dAr >= 0) rcv[dAr] = 1;
    wsync();
    { const unsigned long long rM = __ballot(rcv[l] != 0), dM = __ballot(dAr < 0);
      if (dAr < 0) dAr = kthSetBit(~rM, __popcll(dM & ((1ull << l) - 1ull))); }
    wsync();
    rcv[l] = 0; wsync();
    if (dBr >= 0) rcv[dBr] = 1;
    wsync();
    { const unsigned long long rM = __ballot(rcv[l] != 0), dM = __ballot(dBr < 0);
      if (dBr < 0) dBr = kthSetBit(~rM, __popcll(dM & ((1ull << l) - 1ull))); }
    const int uA = ownP[2*l], uB = ownP[2*l+1];
    if (bid == 0) {   // meta (R1 layout)
      int* M = meta + l * MSTRIDE;
      M[0] = dAr * 4; M[1] = dBr * 4;
      const float s1A = (splitRole[l] == 0) ? 1.f : 0.f, s1B = (splitRole[l] == 1) ? 1.f : 0.f;
      M[2] = __float_as_int(s1A); M[3] = __float_as_int(s1B);
      const float s2 = split2[l] ? 1.f : 0.f;
      M[4] = __float_as_int(s1A * s2); M[5] = __float_as_int(s1B * s2);
      M[6] = ((uA >= 0) ? uA : 128 + l) * 4;
      M[7] = ((uB >= 0) ? uB : 192 + l) * 4;
      M[8] = (uA >= 0) ? uA : 0;
      M[9] = (uB >= 0) ? uB : 0;
    }
    // closed-form per-lane ranges (validated in R4)
    const int ci = contIdx[l];
    int p1 = -1, br = 0, cnt1 = 0;
    if (ci) {
      const int o = contOwn[l];
      p1 = ownP[2*o + splitRole[o]];
      br = (CR - pF0L[p1]) + ((ci == 2) ? CR : 0);
      cnt1 = degL[p1] - br; if (cnt1 > CR) cnt1 = CR;
    }
    int fA = 0, tA = -1;
    if (uA >= 0) { fA = pF0L[uA]; const int rm = CR - fA; const int dd = degL[uA]; tA = dd < rm ? dd : rm; }
    int fB = 0, tB = -1;
    if (uB >= 0) { fB = pF0L[uB]; const int rm = CR - fB; const int dd = degL[uB]; tB = dd < rm ? dd : rm; }
    // sliced fill: this block writes slots s % 4 == bid
    for (int s = bid; s < CR; s += 4) {
      int post = -1, rank = 0, isB = 0;
      if (ci && s < cnt1)                          { post = p1; rank = br + s; }
      else if (uA >= 0 && s >= fA && s < fA + tA)  { post = uA; rank = s - fA; }
      else if (uB >= 0 && s >= fB && s < fB + tB)  { post = uB; rank = s - fB; isB = 1; }
      const int postc = (post >= 0) ? post : 0;    // shfl outside divergence
      const unsigned long long plo = shfl_u64(cLo, postc);
      const unsigned long long phi = shfl_u64(cHi, postc);
      float4 p4 = make_float4(0.f, 0.f, 0.f, 0.f);
      float2 p2 = make_float2(0.f, 0.f);
      int ad = 0;
      if (post >= 0) {
        const int c = __popcll(plo);
        const int pre = (rank < c) ? (18 + kthSetBit(plo, rank)) : (82 + kthSetBit(phi, rank - c));
        const int idx = pre * UNITS + post;
        const float sg_ = sigma[idx];
        const float nsgl = -sg_ * LOG2E, msl = mu[idx] * sg_ * LOG2E;
        const float wd = w[idx], wn = wd * erev[idx];
        p4 = make_float4(nsgl, msl, isB ? 0.f : wn, isB ? 0.f : wd);
        p2 = isB ? make_float2(wn, wd) : make_float2(0.f, 0.f);
        ad = pre * 4;
      }
      recP4[s*64 + l] = p4; recP2[s*64 + l] = p2; recAd[s*64 + l] = ad;
    }
  } else {
    // ================= SENSORY family =================
    unsigned long long cS = 0ull;   // bit r: pre r (0..63)
    {
      const int col = 50 + l;
      for (int base = 0; base < 64; base += 16) {
        float mv[16];
#pragma unroll
        for (int q = 0; q < 16; ++q) mv[q] = smask[(base + q)*UNITS + col];
#pragma unroll
        for (int q = 0; q < 16; ++q) if (mv[q] != 0.f) cS |= (1ull << (base + q));
      }
    }
    const int dreg = __popcll(cS);
    degL[l] = dreg;
    wsync();
    {   // greedy bin-pack (NP=64, C=CS)
      int lam = 0, f = 0, pc = 0;
      for (int p = 0; p < 64; ++p) {
        const int dd = __shfl(dreg, p);
        if (pc == 2 || f == CS || dd > 3*CS - f) { ++lam; f = 0; pc = 0; }
        if (lam > 63) lam = 63;
        if (l == 0) { pF0L[p] = f; ownP[2*lam + pc] = p; }
        const int owner = lam, role = pc; ++pc;
        const int take = dd < (CS - f) ? dd : (CS - f);
        f += take; int rem = dd - take;
        if (rem > 0) {
          if (l == 0) { splitRole[owner] = role; split2[owner] = (rem > CS) ? 1 : 0; }
          ++lam; if (lam > 63) lam = 63;
          if (l == 0) { contIdx[lam] = 1; contOwn[lam] = owner; }
          pc = 1;
          const int t2 = rem < CS ? rem : CS; f = t2; rem -= t2;
          if (rem > 0) {
            ++lam; if (lam > 63) lam = 63;
            if (l == 0) { contIdx[lam] = 2; contOwn[lam] = owner; }
            pc = 1; f = rem;
          }
        }
      }
    }
    wsync();
    // routing: partial-accumulator pushes
    int dAs = (contIdx[l] == 1) ? contOwn[l] : -1;
    int dBs = (contIdx[l] == 2) ? contOwn[l] : -1;
    rcv[l] = 0; wsync();
    if (dAs >= 0) rcv[dAs] = 1;
    wsync();
    { const unsigned long long rM = __ballot(rcv[l] != 0), dM = __ballot(dAs < 0);
      if (dAs < 0) dAs = kthSetBit(~rM, __popcll(dM & ((1ull << l) - 1ull))); }
    wsync();
    rcv[l] = 0; wsync();
    if (dBs >= 0) rcv[dBs] = 1;
    wsync();
    { const unsigned long long rM = __ballot(rcv[l] != 0), dM = __ballot(dBs < 0);
      if (dBs < 0) dBs = kthSetBit(~rM, __popcll(dM & ((1ull << l) - 1ull))); }
    wsync();
    // routing: (a,b) route to canonical lanes (needed only for meta; cheap)
    int rAs = (ownP[2*l]   >= 0) ? canonLane(50 + ownP[2*l])   : -1;
    int rBs = (ownP[2*l+1] >= 0) ? canonLane(50 + ownP[2*l+1]) : -1;
    rcv[l] = 0; wsync();
    if (rAs >= 0) rcv[rAs] = 1;
    wsync();
    const int isRcvA = rcv[l];
    { const unsigned long long rM = __ballot(isRcvA != 0), dM = __ballot(rAs < 0);
      if (rAs < 0) rAs = kthSetBit(~rM, __popcll(dM & ((1ull << l) - 1ull))); }
    wsync();
    rcv[l] = 0; wsync();
    if (rBs >= 0) rcv[rBs] = 1;
    wsync();
    { const unsigned long long rM = __ballot(rcv[l] != 0), dM = __ballot(rBs < 0);
      if (rBs < 0) rBs = kthSetBit(~rM, __popcll(dM & ((1ull << l) - 1ull))); }
    const int pAs = ownP[2*l], pBs = ownP[2*l+1];
    if (bid == 4) {   // meta (R1 layout)
      int* M = meta + l * MSTRIDE;
      M[10] = dAs * 4; M[11] = dBs * 4;
      const float s1A = (splitRole[l] == 0) ? 1.f : 0.f, s1B = (splitRole[l] == 1) ? 1.f : 0.f;
      M[12] = __float_as_int(s1A); M[13] = __float_as_int(s1B);
      const float s2 = split2[l] ? 1.f : 0.f;
      M[14] = __float_as_int(s1A * s2); M[15] = __float_as_int(s1B * s2);
      M[16] = rAs * 4; M[17] = rBs * 4;
      M[18] = __float_as_int(isRcvA ? 1.f : 0.f);
      M[19] = __float_as_int(isRcvA ? 0.f : 1.f);
      M[20] = (pAs >= 0) ? 50 + pAs : 0;
      M[21] = (pBs >= 0) ? 50 + pBs : 0;
    }
    // closed-form per-lane ranges
    const int ci = contIdx[l];
    int p1 = -1, br = 0, cnt1 = 0;
    if (ci) {
      const int o = contOwn[l];
      p1 = ownP[2*o + splitRole[o]];
      br = (CS - pF0L[p1]) + ((ci == 2) ? CS : 0);
      cnt1 = degL[p1] - br; if (cnt1 > CS) cnt1 = CS;
    }
    int fA = 0, tA = -1;
    if (pAs >= 0) { fA = pF0L[pAs]; const int rm = CS - fA; const int dd = degL[pAs]; tA = dd < rm ? dd : rm; }
    int fB = 0, tB = -1;
    if (pBs >= 0) { fB = pF0L[pBs]; const int rm = CS - fB; const int dd = degL[pBs]; tB = dd < rm ? dd : rm; }
    // sliced fill: block (bid-4) writes slots s % 4 == bid-4
    for (int s = bid - 4; s < CS; s += 4) {
      int post = -1, rank = 0, isB = 0;
      if (ci && s < cnt1)                            { post = p1;  rank = br + s; }
      else if (pAs >= 0 && s >= fA && s < fA + tA)   { post = pAs; rank = s - fA; }
      else if (pBs >= 0 && s >= fB && s < fB + tB)   { post = pBs; rank = s - fB; isB = 1; }
      const int postc = (post >= 0) ? post : 0;      // shfl outside divergence
      const unsigned long long pm = shfl_u64(cS, postc);
      float4 p4 = make_float4(0.f, 0.f, 0.f, 0.f);
      float2 p2 = make_float2(0.f, 0.f);
      int ad = 0;
      if (post >= 0) {
        const int pre = kthSetBit(pm, rank);
        const int idx = pre * UNITS + 50 + post;
        const float sg_ = ssg[idx];
        const float nsgl = -sg_ * LOG2E, msl = smu[idx] * sg_ * LOG2E;
        const float wd = sw[idx], wn = wd * serev[idx];
        p4 = make_float4(nsgl, msl, isB ? 0.f : wn, isB ? 0.f : wd);
        p2 = isB ? make_float2(wn, wd) : make_float2(0.f, 0.f);
        ad = pre * 4;
      }
      senP4[s*64 + l] = p4; senP2[s*64 + l] = p2; senAd[s*64 + l] = ad;
    }
  }
}

// ---------------------------------------------------------------------------
// Run kernel: R1 verbatim (proven 277.4 us).
// ---------------------------------------------------------------------------
__global__ __launch_bounds__(64, 2) void ltc_run(
    const float* __restrict__ obs,     const float* __restrict__ hidden,
    const float* __restrict__ input_w, const float* __restrict__ input_b,
    const float* __restrict__ gleak,   const float* __restrict__ vleak,
    const float* __restrict__ cm,
    const float* __restrict__ q_w1, const float* __restrict__ q_b1,
    const float* __restrict__ q_w2, const float* __restrict__ q_b2,
    const float4* __restrict__ recP4, const float2* __restrict__ recP2,
    const int* __restrict__ recAd,
    const float4* __restrict__ senP4, const float2* __restrict__ senP2,
    const int* __restrict__ senAd,
    const int* __restrict__ meta, float* __restrict__ out, int B)
{
  const int l = threadIdx.x, b = blockIdx.x;
  __shared__ float mirror[256];   // [0..113] units, [128..255] scratch sinks
  char* mbase = (char*)mirror;

  float rNS[CR], rMS[CR]; v2f rWA[CR], rWB[CR]; int rad[CR];
#pragma unroll
  for (int s = 0; s < CR; ++s) {
    const float4 p4 = recP4[s*64 + l]; const float2 p2 = recP2[s*64 + l];
    rNS[s] = p4.x; rMS[s] = p4.y; rWA[s] = (v2f){p4.z, p4.w};
    rWB[s] = (v2f){p2.x, p2.y}; rad[s] = recAd[s*64 + l];
  }
  float sNS[CS], sMS[CS]; v2f sWA[CS], sWB[CS]; int sad[CS];
#pragma unroll
  for (int s = 0; s < CS; ++s) {
    const float4 p4 = senP4[s*64 + l]; const float2 p2 = senP2[s*64 + l];
    sNS[s] = p4.x; sMS[s] = p4.y; sWA[s] = (v2f){p4.z, p4.w};
    sWB[s] = (v2f){p2.x, p2.y}; sad[s] = senAd[s*64 + l];
  }

  const int* M = meta + l * MSTRIDE;
  const int   rPush1 = M[0], rPush2 = M[1];
  const v2f gR1A = {__int_as_float(M[2]), __int_as_float(M[2])};
  const v2f gR1B = {__int_as_float(M[3]), __int_as_float(M[3])};
  const v2f gR2A = {__int_as_float(M[4]), __int_as_float(M[4])};
  const v2f gR2B = {__int_as_float(M[5]), __int_as_float(M[5])};
  const int   rWrA = M[6], rWrB = M[7], rUA = M[8], rUB = M[9];
  const int   sPush1 = M[10], sPush2 = M[11];
  const v2f gS1A = {__int_as_float(M[12]), __int_as_float(M[12])};
  const v2f gS1B = {__int_as_float(M[13]), __int_as_float(M[13])};
  const v2f gS2A = {__int_as_float(M[14]), __int_as_float(M[14])};
  const v2f gS2B = {__int_as_float(M[15]), __int_as_float(M[15])};
  const int   sRtA = M[16], sRtB = M[17];
  const float sRndA = __int_as_float(M[18]), sRndB = __int_as_float(M[19]);
  const int   sUA = M[20], sUB = M[21];

  const float cmA  = cm[rUA]*6.f, glvA  = gleak[rUA]*vleak[rUA], cgA  = cm[rUA]*6.f + gleak[rUA] + EPS;
  const float cmB  = cm[rUB]*6.f, glvB  = gleak[rUB]*vleak[rUB], cgB  = cm[rUB]*6.f + gleak[rUB] + EPS;
  const float cmSA = cm[sUA]*6.f, glvSA = gleak[sUA]*vleak[sUA], cgSA = cm[sUA]*6.f + gleak[sUA] + EPS;
  const float cmSB = cm[sUB]*6.f, glvSB = gleak[sUB]*vleak[sUB], cgSB = cm[sUB]*6.f + gleak[sUB] + EPS;

  const bool ownA  = (rWrA < 512), ownB  = (rWrB < 512);
  const bool ownSA = (sUA != 0),   ownSB = (sUB != 0);
  const v2f initRA = ownA  ? (v2f){glvA,  cgA}  : (v2f){0.f, EPS};
  const v2f initRB = ownB  ? (v2f){glvB,  cgB}  : (v2f){0.f, EPS};
  const v2f initSA = ownSA ? (v2f){glvSA, cgSA} : (v2f){0.f, EPS};
  const v2f initSB = ownSB ? (v2f){glvSB, cgSB} : (v2f){0.f, EPS};

  const int  iUnit = (l < 50) ? 64 + l : l;
  const int  iWr   = iUnit * 4;
  float vIn = hidden[(size_t)b*UNITS + iUnit];
  float vPA = hidden[(size_t)b*UNITS + rUA];
  float vPB = hidden[(size_t)b*UNITS + rUB];

  mirror[l] = hidden[(size_t)b*UNITS + l];
  if (l < 50) mirror[64 + l] = hidden[(size_t)b*UNITS + 64 + l];

  const float iw = input_w[l], ibv = input_b[l];
  const float* ob = obs + (size_t)b*(TSTEPS*SDIM) + l;

  // ---- prologue: full sensory eval for t=0 ----
  float aI, bI;
  {
    const float xi = fmaf(ob[0], iw, ibv);
    float uu[CS];
#pragma unroll
    for (int s = 0; s < CS; ++s) {
      float z = fmaf(bperm(sad[s], xi), sNS[s], sMS[s]);
      z = fminf(z, 30.f);
      uu[s] = 1.f + __builtin_amdgcn_exp2f(z);
    }
    float sg[CS];
#pragma unroll
    for (int q = 0; q < 4; ++q) {
      const float p = uu[2*q] * uu[2*q+1];
      const float r = __builtin_amdgcn_rcpf(p);
      sg[2*q]   = uu[2*q+1] * r;
      sg[2*q+1] = uu[2*q]   * r;
    }
    sg[8] = __builtin_amdgcn_rcpf(uu[8]);
    v2f cA = {0.f,0.f}, cB = {0.f,0.f};
#pragma unroll
    for (int s = 0; s < CS; ++s) {
      const v2f s2 = {sg[s], sg[s]};
      cA = fma2(sWA[s], s2, cA);
      cB = fma2(sWB[s], s2, cB);
    }
    const v2f m1 = {dperm(sPush1, cA.x), dperm(sPush1, cA.y)};
    const v2f m2 = {dperm(sPush2, cA.x), dperm(sPush2, cA.y)};
    v2f tA = fma2(gS1A, m1, cA); tA = fma2(gS2A, m2, tA);
    v2f tB = fma2(gS1B, m1, cB); tB = fma2(gS2B, m2, tB);
    const float rdA = __builtin_amdgcn_rcpf(cgSA + tA.y);
    const float aA = cmSA * rdA, bA = (glvSA + tA.x) * rdA;
    const float rdB = __builtin_amdgcn_rcpf(cgSB + tB.y);
    const float aB = cmSB * rdB, bB = (glvSB + tB.x) * rdB;
    const float ra1 = dperm(sRtA, aA), rb1 = dperm(sRtA, bA);
    const float ra2 = dperm(sRtB, aB), rb2 = dperm(sRtB, bB);
    aI = sRndA*ra1 + sRndB*ra2;
    bI = sRndA*rb1 + sRndB*rb2;
  }

  float xiN = fmaf(ob[SDIM], iw, ibv);   // xi(1)
  float xrC = ob[2*SDIM];                // obs(2)
  float su[CS];
  v2f acA = initSA, acB = initSB;
  v2f tSA = {0.f,0.f}, tSB = {0.f,0.f};
  float aIn = 0.f, bIn = 0.f;

  auto unfold = [&](auto chunk) {
    wsync();
    float uu[CR];
#pragma unroll
    for (int s = 0; s < CR; ++s) {
      const float pv = *(const float*)(mbase + rad[s]);
      const float z = fmaf(pv, rNS[s], rMS[s]);   // z <= 20.8 always: no clamp
      uu[s] = 1.f + __builtin_amdgcn_exp2f(z);
    }
    chunk();
    float sg[CR];
#pragma unroll
    for (int q = 0; q < 5; ++q) {
      const float p = uu[2*q] * uu[2*q+1];
      const float r = __builtin_amdgcn_rcpf(p);
      sg[2*q]   = uu[2*q+1] * r;
      sg[2*q+1] = uu[2*q]   * r;
    }
    {   // triple-shared rcp for slots 10,11,12
      const float p01 = uu[10]*uu[11];
      const float r = __builtin_amdgcn_rcpf(p01*uu[12]);
      const float t12 = uu[12]*r;
      sg[10] = uu[11]*t12; sg[11] = uu[10]*t12; sg[12] = p01*r;
    }
    v2f a0 = initRA, a1 = {0.f,0.f}, b0 = initRB, b1 = {0.f,0.f};
#pragma unroll
    for (int s = 0; s < CR; ++s) {
      const v2f s2 = {sg[s], sg[s]};
      if (s & 1) { a1 = fma2(rWA[s], s2, a1); b1 = fma2(rWB[s], s2, b1); }
      else       { a0 = fma2(rWA[s], s2, a0); b0 = fma2(rWB[s], s2, b0); }
    }
    v2f aA = a0 + a1, aB = b0 + b1;
    const v2f m1 = {dperm(rPush1, aA.x), dperm(rPush1, aA.y)};
    const v2f m2 = {dperm(rPush2, aA.x), dperm(rPush2, aA.y)};
    v2f tA = fma2(gR1A, m1, aA); tA = fma2(gR2A, m2, tA);
    v2f tB = fma2(gR1B, m1, aB); tB = fma2(gR2B, m2, tB);
    const float dAq = tA.y, dBq = tB.y;
    const float rr = __builtin_amdgcn_rcpf(dAq * dBq);
    vPA = fmaf(cmA, vPA, tA.x) * (dBq * rr);
    vPB = fmaf(cmB, vPB, tB.x) * (dAq * rr);
    vIn = fmaf(aI, vIn, bI);
    wsync();
    *(float*)(mbase + rWrA) = vPA;
    *(float*)(mbase + rWrB) = vPB;
    *(float*)(mbase + iWr)  = vIn;
  };

  auto sExp = [&](int s) {
    float z = fmaf(bperm(sad[s], xiN), sNS[s], sMS[s]);
    z = fminf(z, 30.f);         // KEEP: sensory z can reach ~75 unclamped
    su[s] = 1.f + __builtin_amdgcn_exp2f(z);
  };
  auto sPair = [&](int s0) {
    const float p = su[s0] * su[s0+1];
    const float r = __builtin_amdgcn_rcpf(p);
    const float g0 = su[s0+1] * r, g1 = su[s0] * r;
    acA = fma2(sWA[s0],   (v2f){g0,g0}, acA);
    acA = fma2(sWA[s0+1], (v2f){g1,g1}, acA);
    acB = fma2(sWB[s0],   (v2f){g0,g0}, acB);
    acB = fma2(sWB[s0+1], (v2f){g1,g1}, acB);
  };

#pragma unroll 1
  for (int t = 0; t < TSTEPS; ++t) {
    unfold([&]{ sExp(0); sExp(1); });
    unfold([&]{ sExp(2); sExp(3); sPair(0); });
    unfold([&]{ sExp(4); sExp(5); sPair(2); });
    unfold([&]{ sExp(6); sExp(7); sExp(8); sPair(4); });
    unfold([&]{
      const float p67 = su[6] * su[7];
      const float r = __builtin_amdgcn_rcpf(p67 * su[8]);
      const float t67 = su[8] * r;
      const float g6 = su[7]*t67, g7 = su[6]*t67, g8 = p67*r;
      acA = fma2(sWA[6], (v2f){g6,g6}, acA); acB = fma2(sWB[6], (v2f){g6,g6}, acB);
      acA = fma2(sWA[7], (v2f){g7,g7}, acA); acB = fma2(sWB[7], (v2f){g7,g7}, acB);
      acA = fma2(sWA[8], (v2f){g8,g8}, acA); acB = fma2(sWB[8], (v2f){g8,g8}, acB);
      const v2f m1 = {dperm(sPush1, acA.x), dperm(sPush1, acA.y)};
      const v2f m2 = {dperm(sPush2, acA.x), dperm(sPush2, acA.y)};
      tSA = fma2(gS1A, m1, acA); tSA = fma2(gS2A, m2, tSA);
      tSB = fma2(gS1B, m1, acB); tSB = fma2(gS2B, m2, tSB);
    });
    unfold([&]{
      const float dA_ = tSA.y, dB_ = tSB.y;
      const float rr = __builtin_amdgcn_rcpf(dA_ * dB_);
      const float rdA = dB_ * rr, rdB = dA_ * rr;
      const float aA = cmSA * rdA, bA = tSA.x * rdA;
      const float aB = cmSB * rdB, bB = tSB.x * rdB;
      const float ra1 = dperm(sRtA, aA), rb1 = dperm(sRtA, bA);
      const float ra2 = dperm(sRtB, aB), rb2 = dperm(sRtB, bB);
      aIn = sRndA*ra1 + sRndB*ra2;
      bIn = sRndA*rb1 + sRndB*rb2;
    });
    aI = aIn; bI = bIn;
    xiN = fmaf(xrC, iw, ibv);                      // xi(t+2)
    const int tn = (t + 3 < TSTEPS) ? (t + 3) : (TSTEPS - 1);
    xrC = ob[tn * SDIM];                           // obs(t+3), clamped
    acA = initSA; acB = initSB;
  }
  wsync();

  // ---- outputs: h then Q head ----
  float* __restrict__ outH = out + (size_t)B * ACT;
  outH[(size_t)b*UNITS + l] = mirror[l];
  if (l < 50) outH[(size_t)b*UNITS + 64 + l] = mirror[64 + l];

  const int j2 = (l < 50) ? 64 + l : l;
  float h1 = q_b1[l], h2 = q_b1[j2];
  for (int i = 0; i < UNITS; ++i) {
    const float hv = mirror[i];
    h1 = fmaf(hv, q_w1[i*UNITS + l],  h1);
    h2 = fmaf(hv, q_w1[i*UNITS + j2], h2);
  }
  h1 = fmaxf(h1, 0.f); h2 = fmaxf(h2, 0.f);
  wsync();
  mirror[l] = h1;
  if (l < 50) mirror[64 + l] = h2;
  wsync();
  if (l < ACT) {
    float q = q_b2[l];
    for (int i = 0; i < UNITS; ++i) q = fmaf(mirror[i], q_w2[i*ACT + l], q);
    out[(size_t)b*ACT + l] = q;
  }
}

extern "C" void kernel_launch(void* const* d_in, const int* in_sizes, int n_in,
                              void* d_out, int out_size, void* d_ws, size_t ws_size,
                              hipStream_t stream)
{
  const float* obs           = (const float*)d_in[0];
  const float* hidden        = (const float*)d_in[1];
  const float* input_w       = (const float*)d_in[2];
  const float* input_b       = (const float*)d_in[3];
  const float* sensory_w     = (const float*)d_in[4];
  const float* sensory_mu    = (const float*)d_in[5];
  const float* sensory_sigma = (const float*)d_in[6];
  const float* sensory_erev  = (const float*)d_in[7];
  const float* sensory_mask  = (const float*)d_in[8];
  const float* w             = (const float*)d_in[9];
  const float* mu            = (const float*)d_in[10];
  const float* sigma         = (const float*)d_in[11];
  const float* erev          = (const float*)d_in[12];
  const float* mask          = (const float*)d_in[13];
  const float* gleak         = (const float*)d_in[14];
  const float* vleak         = (const float*)d_in[15];
  const float* cm            = (const float*)d_in[16];
  const float* q_w1          = (const float*)d_in[17];
  const float* q_b1          = (const float*)d_in[18];
  const float* q_w2          = (const float*)d_in[19];
  const float* q_b2          = (const float*)d_in[20];

  char* ws = (char*)d_ws;
  float4* recP4 = (float4*)(ws);            // 13*64*16 = 13312
  float2* recP2 = (float2*)(ws + 13312);    // 13*64*8  = 6656  -> 19968
  int*    recAd = (int*)   (ws + 19968);    // 13*64*4  = 3328  -> 23296
  float4* senP4 = (float4*)(ws + 23296);    // 9*64*16  = 9216  -> 32512
  float2* senP2 = (float2*)(ws + 32512);    // 9*64*8   = 4608  -> 37120
  int*    senAd = (int*)   (ws + 37120);    // 9*64*4   = 2304  -> 39424
  int*    meta  = (int*)   (ws + 39424);    // 64*24*4  = 6144  -> 45568

  build_all<<<8, 64, 0, stream>>>(
      w, mu, sigma, erev, mask,
      sensory_w, sensory_mu, sensory_sigma, sensory_erev, sensory_mask,
      recP4, recP2, recAd, senP4, senP2, senAd, meta);

  const int B = in_sizes[0] / (TSTEPS * SDIM);
  ltc_run<<<B, 64, 0, stream>>>(
      obs, hidden, input_w, input_b, gleak, vleak, cm,
      q_w1, q_b1, q_w2, q_b2,
      recP4, recP2, recAd, senP4, senP2, senAd, meta,
      (float*)d_out, B);
}